// Round 7
// baseline (714.159 us; speedup 1.0000x reference)
//
#include <hip/hip_runtime.h>

#define SEQLEN 2048
#define NHEADS 64
#define PDIM 64
#define NSTATE 128
#define CSIZE 256
#define NCHUNK 8
#define DINNER 4096
#define CONVD 4352
#define PROJD 8512

using s8v = __attribute__((ext_vector_type(8))) short;
using f4v = __attribute__((ext_vector_type(4))) float;
using bf8v = __attribute__((ext_vector_type(8))) __bf16;

__device__ __forceinline__ short f2bf(float x) {
  union { float f; unsigned u; } t; t.f = x;
  unsigned r = t.u + 0x7FFFu + ((t.u >> 16) & 1u);
  return (short)(r >> 16);
}
__device__ __forceinline__ float bf2f(short s) {
  union { unsigned u; float f; } t;
  t.u = ((unsigned)(unsigned short)s) << 16;
  return t.f;
}

__device__ __forceinline__ f4v mfma_bf16(s8v a, s8v b, f4v c) {
  return __builtin_amdgcn_mfma_f32_16x16x32_bf16(
      __builtin_bit_cast(bf8v, a), __builtin_bit_cast(bf8v, b), c, 0, 0, 0);
}

// async global->LDS, 16B per lane; LDS dest must be lane-contiguous
__device__ __forceinline__ void gll16(const void* g, void* l) {
  __builtin_amdgcn_global_load_lds(
      (const __attribute__((address_space(1))) unsigned*)g,
      (__attribute__((address_space(3))) unsigned*)l, 16, 0, 0);
}

// ---------------------------------------------------------------- casts
__global__ __launch_bounds__(256) void cast_bf16_kernel(
    const float* __restrict__ in, short* __restrict__ out, int n4) {
  int i = blockIdx.x * 256 + threadIdx.x;
  if (i < n4) {
    float4 v = ((const float4*)in)[i];
    short4 o;
    o.x = f2bf(v.x); o.y = f2bf(v.y); o.z = f2bf(v.z); o.w = f2bf(v.w);
    ((short4*)out)[i] = o;
  }
}

// ===================== GEMM1: 256x256 8-phase pipelined (m201 template) ====
// FROZEN at the r1/r2/r6-measured form (182-184us, MfmaUtil 33.4). The
// dt_bias+softplus epilogue fusion poisoned the K-loop codegen (r3-r5 all
// ~239us); any edit to this kernel needs a full A/B. Do not touch.

#define G1_STAGE_A(dst, h, kt) do {                                          \
    _Pragma("unroll")                                                        \
    for (int it_ = 0; it_ < 2; ++it_) {                                      \
      int ci_ = it_ * 512 + tid;                                             \
      int r_ = ci_ >> 3;                                                     \
      int g_ = ((ci_ & 7) ^ (r_ & 7)) << 3;                                  \
      gll16(&A[(size_t)(tm0 + (h) * 128 + r_) * 2048 + (kt) * 64 + g_],      \
            &(dst)[(h) * 8192 + ci_ * 8]);                                   \
    }                                                                        \
  } while (0)

#define G1_STAGE_B(dst, h, kt) do {                                          \
    _Pragma("unroll")                                                        \
    for (int it_ = 0; it_ < 2; ++it_) {                                      \
      int ci_ = it_ * 512 + tid;                                             \
      int r_ = ci_ >> 3;                                                     \
      int g_ = ((ci_ & 7) ^ (r_ & 7)) << 3;                                  \
      int br_ = tn0 + (h) * 128 + r_;                                        \
      if (br_ > 8511) br_ = 8511; /* dt-strip tile over-reads: clamp */      \
      gll16(&B[(size_t)br_ * 2048 + (kt) * 64 + g_],                         \
            &(dst)[(h) * 8192 + ci_ * 8]);                                   \
    }                                                                        \
  } while (0)

#define RD_A(m, ks) \
  (*(const s8v*)&Ad[(wm + (m) * 16 + lr) * 64 + (((ks) * 4 + q) ^ sw7) * 8])
#define RD_B(n, ks) \
  (*(const s8v*)&Bd[(wn + (n) * 16 + lr) * 64 + (((ks) * 4 + q) ^ sw7) * 8])

#define G1_MFMA2(m0, x00, x01, x10, x11) do {                                \
    __builtin_amdgcn_s_setprio(1);                                           \
    _Pragma("unroll") for (int n = 0; n < 4; ++n)                            \
      acc[m0][n] = mfma_bf16(x00, bk0[n], acc[m0][n]);                       \
    _Pragma("unroll") for (int n = 0; n < 4; ++n)                            \
      acc[m0][n] = mfma_bf16(x01, bk1[n], acc[m0][n]);                       \
    _Pragma("unroll") for (int n = 0; n < 4; ++n)                            \
      acc[(m0) + 1][n] = mfma_bf16(x10, bk0[n], acc[(m0) + 1][n]);           \
    _Pragma("unroll") for (int n = 0; n < 4; ++n)                            \
      acc[(m0) + 1][n] = mfma_bf16(x11, bk1[n], acc[(m0) + 1][n]);           \
    __builtin_amdgcn_s_setprio(0);                                           \
  } while (0)

__global__ __launch_bounds__(512, 2) void gemm1_256(
    const short* __restrict__ A, const short* __restrict__ B,
    short* __restrict__ z, short* __restrict__ xbc, float* __restrict__ dtb) {
  const int NT = 32;  // 2048 / 64
  // XCD-bijective swizzle (544 % 8 == 0) then 4-high panel map for L2 reuse
  const int bid = blockIdx.x;
  const int sid = (bid & 7) * 68 + (bid >> 3);
  const int panel = sid / 136, rem = sid % 136;
  const int bx = rem >> 2, by = panel * 4 + (rem & 3);
  const int tm0 = by * 256, tn0 = bx * 256;
  __shared__ alignas(16) short lds[65536];  // 128 KB
  const int tid = threadIdx.x;
  const int lane = tid & 63, wid = tid >> 6;
  const int wm = (wid >> 2) * 128, wn = (wid & 3) * 64;
  const int lr = lane & 15, q = lane >> 4;
  const int sw7 = lr & 7;

  f4v acc[8][4];
#pragma unroll
  for (int m = 0; m < 8; ++m)
#pragma unroll
    for (int n = 0; n < 4; ++n)
#pragma unroll
      for (int r = 0; r < 4; ++r) acc[m][n][r] = 0.f;

  // prologue: tile0 {Ah0,Ah1,Bh0,Bh1}, tile1 {Bh0,Bh1}  (12 loads/thread)
  {
    short* A0 = lds;
    short* B0 = lds + 16384;
    short* B1 = lds + 49152;
    G1_STAGE_A(A0, 0, 0); G1_STAGE_A(A0, 1, 0);
    G1_STAGE_B(B0, 0, 0); G1_STAGE_B(B0, 1, 0);
    G1_STAGE_B(B1, 0, 1); G1_STAGE_B(B1, 1, 1);
    // drain A(0),B(0); leave B(1) in flight
    asm volatile("s_waitcnt vmcnt(4)" ::: "memory");
    __builtin_amdgcn_s_barrier();
  }

  for (int t = 0; t < NT; ++t) {
    short* Ad = lds + ((t & 1) << 15);
    short* Bd = Ad + 16384;
    short* An = lds + (((t + 1) & 1) << 15);
    s8v bk0[4], bk1[4];
    // ---- p0: all B-frags + a0,a1; stage Ah0(t+1)
    {
#pragma unroll
      for (int n = 0; n < 4; ++n) { bk0[n] = RD_B(n, 0); bk1[n] = RD_B(n, 1); }
      s8v a00 = RD_A(0, 0), a01 = RD_A(0, 1);
      s8v a10 = RD_A(1, 0), a11 = RD_A(1, 1);
      if (t + 1 < NT) G1_STAGE_A(An, 0, t + 1);
      __builtin_amdgcn_s_barrier();
      asm volatile("s_waitcnt lgkmcnt(0)" ::: "memory");
      G1_MFMA2(0, a00, a01, a10, a11);
      __builtin_amdgcn_s_barrier();
    }
    // ---- p1
    {
      s8v a00 = RD_A(2, 0), a01 = RD_A(2, 1);
      s8v a10 = RD_A(3, 0), a11 = RD_A(3, 1);
      if (t + 1 < NT) G1_STAGE_A(An, 1, t + 1);
      __builtin_amdgcn_s_barrier();
      asm volatile("s_waitcnt lgkmcnt(0)" ::: "memory");
      G1_MFMA2(2, a00, a01, a10, a11);
      __builtin_amdgcn_s_barrier();
    }
    // ---- p2: B(t+2) h0 into CURRENT B region (dead after p0 reads)
    {
      s8v a00 = RD_A(4, 0), a01 = RD_A(4, 1);
      s8v a10 = RD_A(5, 0), a11 = RD_A(5, 1);
      if (t + 2 < NT) G1_STAGE_B(Bd, 0, t + 2);
      __builtin_amdgcn_s_barrier();
      asm volatile("s_waitcnt lgkmcnt(0)" ::: "memory");
      G1_MFMA2(4, a00, a01, a10, a11);
      __builtin_amdgcn_s_barrier();
    }
    // ---- p3: counted vmcnt validates tile t+1 for p0(t+1)'s reads
    {
      s8v a00 = RD_A(6, 0), a01 = RD_A(6, 1);
      s8v a10 = RD_A(7, 0), a11 = RD_A(7, 1);
      if (t + 2 < NT) G1_STAGE_B(Bd, 1, t + 2);
      if (t < NT - 2) {
        asm volatile("s_waitcnt vmcnt(4)" ::: "memory");
      } else {
        asm volatile("s_waitcnt vmcnt(0)" ::: "memory");
      }
      __builtin_amdgcn_s_barrier();
      asm volatile("s_waitcnt lgkmcnt(0)" ::: "memory");
      G1_MFMA2(6, a00, a01, a10, a11);
      __builtin_amdgcn_s_barrier();
    }
  }

  // ------------------------------ epilogue ------------------------------
  if (bx == 33) {  // dt strip: cols 8448..8511, fp32, wn==0 waves hold them
    if (wn == 0) {
#pragma unroll
      for (int m = 0; m < 8; ++m)
#pragma unroll
        for (int n = 0; n < 4; ++n) {
          int col = n * 16 + lr;
#pragma unroll
          for (int r = 0; r < 4; ++r) {
            int row = tm0 + wm + m * 16 + q * 4 + r;
            dtb[(size_t)row * NHEADS + col] = acc[m][n][r];
          }
        }
    }
    return;
  }
  short* outp; int stride, colbase;
  if (bx < 16) { outp = z;   stride = DINNER; colbase = tn0; }
  else         { outp = xbc; stride = CONVD;  colbase = tn0 - DINNER; }
  short* Cs = lds;  // [128][264] bf16 staging, all pipeline work drained
  for (int h = 0; h < 2; ++h) {
    __syncthreads();
    if ((wid >> 2) == h) {
#pragma unroll
      for (int m = 0; m < 8; ++m)
#pragma unroll
        for (int n = 0; n < 4; ++n)
#pragma unroll
          for (int r = 0; r < 4; ++r)
            Cs[(m * 16 + q * 4 + r) * 264 + wn + n * 16 + lr] =
                f2bf(acc[m][n][r]);
    }
    __syncthreads();
#pragma unroll
    for (int itr = 0; itr < 8; ++itr) {
      int idx = itr * 512 + tid;
      int r = idx >> 5, c8 = (idx & 31) * 8;
      s8v v = *(const s8v*)&Cs[r * 264 + c8];
      *(s8v*)&outp[(size_t)(tm0 + h * 128 + r) * stride + colbase + c8] = v;
    }
  }
}

// ======== GEMM2: 256x128-tile 8-phase, grid 256 = EXACTLY 1 round =========
// out = g @ W_out^T. M=4096, N=2048, K=4096. Block 512 thr (8 waves 2Mx4N,
// per-wave out 128x32). LDS 96KB: buf[2] x { A[256][64], B[128][64] }.

#define G2_STAGE_A(dst, h, kt) do {                                          \
    _Pragma("unroll")                                                        \
    for (int it_ = 0; it_ < 2; ++it_) {                                      \
      int ci_ = it_ * 512 + tid;                                             \
      int r_ = ci_ >> 3;                                                     \
      int g_ = ((ci_ & 7) ^ (r_ & 7)) << 3;                                  \
      gll16(&Ag[(size_t)(tm0 + (h) * 128 + r_) * 4096 + (kt) * 64 + g_],     \
            &(dst)[(h) * 8192 + ci_ * 8]);                                   \
    }                                                                        \
  } while (0)

#define G2_STAGE_B(dst, h, kt) do {                                          \
    int ci_ = tid;                                                           \
    int r_ = ci_ >> 3;                                                       \
    int g_ = ((ci_ & 7) ^ (r_ & 7)) << 3;                                    \
    gll16(&Bg[(size_t)(tn0 + (h) * 64 + r_) * 4096 + (kt) * 64 + g_],        \
          &(dst)[(h) * 4096 + ci_ * 8]);                                     \
  } while (0)

#define RD_A2(m, ks) \
  (*(const s8v*)&Ad[(wm + (m) * 16 + lr) * 64 + (((ks) * 4 + q) ^ sw7) * 8])
#define RD_B2(n, ks) \
  (*(const s8v*)&Bd[(wn + (n) * 16 + lr) * 64 + (((ks) * 4 + q) ^ sw7) * 8])

#define G2_MFMA2(m0, x00, x01, x10, x11) do {                                \
    __builtin_amdgcn_s_setprio(1);                                           \
    _Pragma("unroll") for (int n = 0; n < 2; ++n)                            \
      acc[m0][n] = mfma_bf16(x00, bk0[n], acc[m0][n]);                       \
    _Pragma("unroll") for (int n = 0; n < 2; ++n)                            \
      acc[m0][n] = mfma_bf16(x01, bk1[n], acc[m0][n]);                       \
    _Pragma("unroll") for (int n = 0; n < 2; ++n)                            \
      acc[(m0) + 1][n] = mfma_bf16(x10, bk0[n], acc[(m0) + 1][n]);           \
    _Pragma("unroll") for (int n = 0; n < 2; ++n)                            \
      acc[(m0) + 1][n] = mfma_bf16(x11, bk1[n], acc[(m0) + 1][n]);           \
    __builtin_amdgcn_s_setprio(0);                                           \
  } while (0)

__global__ __launch_bounds__(512, 2) void gemm2_256x128(
    const short* __restrict__ Ag, const short* __restrict__ Bg,
    float* __restrict__ C) {
  const int NT = 64;  // 4096 / 64
  // XCD-bijective swizzle (256 % 8 == 0), 4-high panels
  const int bid = blockIdx.x;
  const int sid = (bid & 7) * 32 + (bid >> 3);
  const int panel = sid >> 6, rem = sid & 63;
  const int bx = rem >> 2, by = panel * 4 + (rem & 3);
  const int tm0 = by * 256, tn0 = bx * 128;
  __shared__ alignas(16) short lds[49152];  // 96 KB
  const int tid = threadIdx.x;
  const int lane = tid & 63, wid = tid >> 6;
  const int wm = (wid >> 2) * 128, wn = (wid & 3) * 32;
  const int lr = lane & 15, q = lane >> 4;
  const int sw7 = lr & 7;

  f4v acc[8][2];
#pragma unroll
  for (int m = 0; m < 8; ++m)
#pragma unroll
    for (int n = 0; n < 2; ++n)
#pragma unroll
      for (int r = 0; r < 4; ++r) acc[m][n][r] = 0.f;

  // prologue: A0 h0,h1 (4) + B0 h0,h1 (2) + B1 h0,h1 (2)
  {
    short* A0 = lds;
    short* B0 = lds + 16384;
    short* B1 = lds + 40960;
    G2_STAGE_A(A0, 0, 0); G2_STAGE_A(A0, 1, 0);
    G2_STAGE_B(B0, 0, 0); G2_STAGE_B(B0, 1, 0);
    G2_STAGE_B(B1, 0, 1); G2_STAGE_B(B1, 1, 1);
    asm volatile("s_waitcnt vmcnt(2)" ::: "memory");  // leave B(1) in flight
    __builtin_amdgcn_s_barrier();
  }

  for (int t = 0; t < NT; ++t) {
    short* Ad = lds + (t & 1) * 24576;
    short* Bd = Ad + 16384;
    short* An = lds + ((t + 1) & 1) * 24576;
    s8v bk0[2], bk1[2];
    // ---- p0
    {
#pragma unroll
      for (int n = 0; n < 2; ++n) { bk0[n] = RD_B2(n, 0); bk1[n] = RD_B2(n, 1); }
      s8v a00 = RD_A2(0, 0), a01 = RD_A2(0, 1);
      s8v a10 = RD_A2(1, 0), a11 = RD_A2(1, 1);
      if (t + 1 < NT) G2_STAGE_A(An, 0, t + 1);
      __builtin_amdgcn_s_barrier();
      asm volatile("s_waitcnt lgkmcnt(0)" ::: "memory");
      G2_MFMA2(0, a00, a01, a10, a11);
      __builtin_amdgcn_s_barrier();
    }
    // ---- p1
    {
      s8v a00 = RD_A2(2, 0), a01 = RD_A2(2, 1);
      s8v a10 = RD_A2(3, 0), a11 = RD_A2(3, 1);
      if (t + 1 < NT) G2_STAGE_A(An, 1, t + 1);
      __builtin_amdgcn_s_barrier();
      asm volatile("s_waitcnt lgkmcnt(0)" ::: "memory");
      G2_MFMA2(2, a00, a01, a10, a11);
      __builtin_amdgcn_s_barrier();
    }
    // ---- p2: B(t+2) h0 into CURRENT B region (dead after p0 reads)
    {
      s8v a00 = RD_A2(4, 0), a01 = RD_A2(4, 1);
      s8v a10 = RD_A2(5, 0), a11 = RD_A2(5, 1);
      if (t + 2 < NT) G2_STAGE_B(Bd, 0, t + 2);
      __builtin_amdgcn_s_barrier();
      asm volatile("s_waitcnt lgkmcnt(0)" ::: "memory");
      G2_MFMA2(4, a00, a01, a10, a11);
      __builtin_amdgcn_s_barrier();
    }
    // ---- p3: counted vmcnt validates tile t+1
    {
      s8v a00 = RD_A2(6, 0), a01 = RD_A2(6, 1);
      s8v a10 = RD_A2(7, 0), a11 = RD_A2(7, 1);
      if (t + 2 < NT) G2_STAGE_B(Bd, 1, t + 2);
      if (t < NT - 2) {
        asm volatile("s_waitcnt vmcnt(2)" ::: "memory");
      } else {
        asm volatile("s_waitcnt vmcnt(0)" ::: "memory");
      }
      __builtin_amdgcn_s_barrier();
      asm volatile("s_waitcnt lgkmcnt(0)" ::: "memory");
      G2_MFMA2(6, a00, a01, a10, a11);
      __builtin_amdgcn_s_barrier();
    }
  }

  // epilogue: fp32 dword scatter (64B/quarter-wave segments)
#pragma unroll
  for (int m = 0; m < 8; ++m)
#pragma unroll
    for (int n = 0; n < 2; ++n) {
      int r0 = tm0 + wm + m * 16 + q * 4;
      int c0 = tn0 + wn + n * 16 + lr;
#pragma unroll
      for (int r = 0; r < 4; ++r)
        C[(size_t)(r0 + r) * 2048 + c0] = acc[m][n][r];
    }
}

// ------------------------------------------------ depthwise conv + SiLU
__global__ __launch_bounds__(256) void conv_silu_kernel(
    const short* __restrict__ xbc, const float* __restrict__ conv_w,
    const float* __restrict__ conv_b, short* __restrict__ xBCc) {
  int cc = blockIdx.x * 256 + threadIdx.x;  // 0..4351
  int bl = blockIdx.y;
  int b = bl >> 11, l = bl & 2047;
  float4 wv = *(const float4*)&conv_w[cc * 4];
  float wk[4] = {wv.x, wv.y, wv.z, wv.w};
  float acc = conv_b[cc];
  const short* pbase = xbc + (size_t)(b * SEQLEN) * CONVD + cc;
#pragma unroll
  for (int k = 0; k < 4; k++) {
    int ls = l - 3 + k;
    if (ls >= 0) acc += bf2f(pbase[(size_t)ls * CONVD]) * wk[k];
  }
  float sv = acc / (1.f + expf(-acc));
  xBCc[(size_t)bl * CONVD + cc] = f2bf(sv);
}

// ----------------------------------------------------- dt softplus (in-place)
__global__ __launch_bounds__(256) void dt_kernel(
    float* __restrict__ dtb, const float* __restrict__ dt_bias) {
  int idx = blockIdx.x * 256 + threadIdx.x;  // < 4096*64
  int hh = idx & 63;
  float v = dtb[idx] + dt_bias[hh];
  dtb[idx] = (v > 20.f) ? v : log1pf(expf(v));
}

// ---------------------------------------- per-chunk states (fp32 VALU)
__global__ __launch_bounds__(256) void ssd_states_kernel(
    const short* __restrict__ xBCc, const float* __restrict__ dtp,
    const float* __restrict__ A_log, short* __restrict__ states,
    float* __restrict__ da_last) {
  const int blk = blockIdx.x;
  const int h = blk & 63, cc = (blk >> 6) & 7, b = blk >> 9;
  const int tid = threadIdx.x;
  __shared__ float dt_s[CSIZE], Acum[CSIZE], w_s[CSIZE];
  __shared__ float xw[64][64];
  __shared__ float Bt[64][NSTATE];
  const size_t row0 = (size_t)(b * SEQLEN + cc * CSIZE);
  dt_s[tid] = dtp[(row0 + tid) * NHEADS + h];
  __syncthreads();
  if (tid == 0) {
    float Aval = -expf(A_log[h]);
    float s = 0.f;
    for (int i = 0; i < CSIZE; i++) { s += dt_s[i]; Acum[i] = s * Aval; }
    da_last[(size_t)(b * NHEADS + h) * NCHUNK + cc] = Acum[CSIZE - 1];
  }
  __syncthreads();
  float total = Acum[CSIZE - 1];
  w_s[tid] = dt_s[tid] * expf(total - Acum[tid]);
  float acc[4][8];
  for (int a = 0; a < 4; a++) for (int j = 0; j < 8; j++) acc[a][j] = 0.f;
  const int pi = (tid & 15) * 4, ni = (tid >> 4) * 8;
  for (int lt = 0; lt < 4; lt++) {
    __syncthreads();
    for (int i = 0; i < 4; i++) {
      int idx = tid + i * 256;
      int r = idx >> 4, c4 = (idx & 15) << 2;
      short4 v = *(const short4*)&xBCc[(row0 + lt * 64 + r) * CONVD + h * PDIM + c4];
      float wl = w_s[lt * 64 + r];
      xw[r][c4 + 0] = bf2f(v.x) * wl;
      xw[r][c4 + 1] = bf2f(v.y) * wl;
      xw[r][c4 + 2] = bf2f(v.z) * wl;
      xw[r][c4 + 3] = bf2f(v.w) * wl;
    }
    for (int i = 0; i < 8; i++) {
      int idx = tid + i * 256;
      int r = idx >> 5, c4 = (idx & 31) << 2;
      short4 v = *(const short4*)&xBCc[(row0 + lt * 64 + r) * CONVD + DINNER + c4];
      Bt[r][c4 + 0] = bf2f(v.x);
      Bt[r][c4 + 1] = bf2f(v.y);
      Bt[r][c4 + 2] = bf2f(v.z);
      Bt[r][c4 + 3] = bf2f(v.w);
    }
    __syncthreads();
    for (int l = 0; l < 64; l++) {
      float4 xv = *(const float4*)&xw[l][pi];
      float4 b0 = *(const float4*)&Bt[l][ni];
      float4 b1 = *(const float4*)&Bt[l][ni + 4];
      float xa[4] = {xv.x, xv.y, xv.z, xv.w};
      float bb[8] = {b0.x, b0.y, b0.z, b0.w, b1.x, b1.y, b1.z, b1.w};
      for (int a = 0; a < 4; a++)
        for (int j = 0; j < 8; j++)
          acc[a][j] += xa[a] * bb[j];
    }
  }
  const size_t sbase = (((size_t)b * NCHUNK + cc) * NHEADS + h) * (PDIM * NSTATE);
  for (int a = 0; a < 4; a++) {
    short o[8];
    for (int j = 0; j < 8; j++) o[j] = f2bf(acc[a][j]);
    *(s8v*)&states[sbase + (size_t)(pi + a) * NSTATE + ni] = *(const s8v*)o;
  }
}

// ---------------- 8-step chunk scan (in-place, s8v vectorized) -----------
// Thread handles 8 CONSECUTIVE elements (16B load/store per chunk) instead
// of 8 stride-256 scalars. Elementwise recurrence: identical arithmetic.
__global__ __launch_bounds__(256) void scan_kernel(
    short* __restrict__ states, const float* __restrict__ da_last) {
  const int bh = blockIdx.x >> 2, sl = blockIdx.x & 3;
  const int b = bh >> 6, h = bh & 63;
  const int tid = threadIdx.x;
  float prev[8];
#pragma unroll
  for (int i = 0; i < 8; i++) prev[i] = 0.f;
  for (int c = 0; c < NCHUNK; c++) {
    const size_t base = (((size_t)b * NCHUNK + c) * NHEADS + h) * (PDIM * NSTATE)
                      + sl * 2048;
    const float d = expf(da_last[(size_t)bh * NCHUNK + c]);
    size_t e0 = base + (size_t)tid * 8;
    s8v sv = *(const s8v*)&states[e0];
    short ov[8];
#pragma unroll
    for (int i = 0; i < 8; i++) {
      float s = bf2f(sv[i]);
      ov[i] = f2bf(prev[i]);
      prev[i] = prev[i] * d + s;
    }
    *(s8v*)&states[e0] = *(const s8v*)ov;
  }
}

// ------------- SSD Y v2: st-outer, C-frags in regs, minimal staging ------
// v1 staged C 4x, prev 4x, B 10x, xdt 10x per block (28 events). v2: prev
// 1x (LDS), C 0x (16 s8v direct from L2-hot global into regs), B 4x,
// xdt 4x. Accumulators for all 4 lt tiles live in regs (64 VGPR).
// Same MFMA count and per-element arithmetic as v1.
__global__ __launch_bounds__(256) void ssd_y_kernel(
    const short* __restrict__ xBCc, const float* __restrict__ dtp,
    const float* __restrict__ A_log, const float* __restrict__ D_param,
    const short* __restrict__ prevs, short* __restrict__ y) {
  const int blk = blockIdx.x;
  const int h = blk & 63, cc = (blk >> 6) & 7, b = blk >> 9;
  const int tid = threadIdx.x;
  const int lane = tid & 63, w = tid >> 6;
  const int lr = lane & 15, q = lane >> 4;
  __shared__ float dt_s[CSIZE];
  __shared__ float Acum[CSIZE];
  __shared__ short PV_s[64][136];   // prev state tile (staged once)
  __shared__ short B_s[64][136];    // B[st] tile (staged per st)
  __shared__ short xdtT[64][72];    // (x*dt)^T [p][l] (staged per st)
  __shared__ short Mt[64][72];      // masked-score / epilogue transpose buf
  const size_t row0 = (size_t)(b * SEQLEN + cc * CSIZE);
  dt_s[tid] = dtp[(row0 + tid) * NHEADS + h];
  __syncthreads();
  if (tid == 0) {
    float Aval = -expf(A_log[h]);
    float s = 0.f;
    for (int i = 0; i < CSIZE; i++) { s += dt_s[i]; Acum[i] = s * Aval; }
  }
  const float Dh = D_param[h];
  const size_t prevbase = (((size_t)b * NCHUNK + cc) * NHEADS + h) * (PDIM * NSTATE);
  const int wl0 = w * 16;

  // stage prev once (concurrent with tid0's Acum fill; barrier publishes both)
#pragma unroll
  for (int i = 0; i < 4; i++) {
    int idx = tid + i * 256;
    int r = idx >> 4, c8 = (idx & 15) << 3;
    *(s8v*)&PV_s[r][c8] = *(const s8v*)&prevs[prevbase + (size_t)r * NSTATE + c8];
  }
  __syncthreads();

  // C-fragments direct from global (L2-hot) + phase A: acc[lt] = C @ prev^T
  s8v cfr[4][4];
  f4v acc[4][4];
#pragma unroll
  for (int lt = 0; lt < 4; lt++) {
#pragma unroll
    for (int ks = 0; ks < 4; ks++)
      cfr[lt][ks] = *(const s8v*)&xBCc[(row0 + lt * 64 + wl0 + lr) * CONVD
                                       + DINNER + NSTATE + ks * 32 + q * 8];
#pragma unroll
    for (int j = 0; j < 4; j++)
#pragma unroll
      for (int r = 0; r < 4; r++) acc[lt][j][r] = 0.f;
#pragma unroll
    for (int ks = 0; ks < 4; ks++)
#pragma unroll
      for (int j = 0; j < 4; j++)
        acc[lt][j] = mfma_bf16(cfr[lt][ks],
            *(const s8v*)&PV_s[j * 16 + lr][ks * 32 + q * 8], acc[lt][j]);
#pragma unroll
    for (int r = 0; r < 4; r++) {
      float e = __expf(Acum[lt * 64 + wl0 + q * 4 + r]);
#pragma unroll
      for (int j = 0; j < 4; j++) acc[lt][j][r] *= e;
    }
  }

  // phase B: st-outer — stage B[st] + xdt[st] once, sweep lt >= st
  for (int st = 0; st < 4; st++) {
#pragma unroll
    for (int i = 0; i < 4; i++) {
      int idx = tid + i * 256;
      int r = idx >> 4, c8 = (idx & 15) << 3;
      *(s8v*)&B_s[r][c8] =
          *(const s8v*)&xBCc[(row0 + st * 64 + r) * CONVD + DINNER + c8];
    }
#pragma unroll
    for (int i = 0; i < 4; i++) {
      int idx = tid + i * 256;
      int r = idx >> 4, c4 = (idx & 15) << 2;
      float dtv = dt_s[st * 64 + r];
      short4 v = *(const short4*)&xBCc[(row0 + st * 64 + r) * CONVD + h * PDIM + c4];
      xdtT[c4 + 0][r] = f2bf(bf2f(v.x) * dtv);
      xdtT[c4 + 1][r] = f2bf(bf2f(v.y) * dtv);
      xdtT[c4 + 2][r] = f2bf(bf2f(v.z) * dtv);
      xdtT[c4 + 3][r] = f2bf(bf2f(v.w) * dtv);
    }
    __syncthreads();
    for (int lt = st; lt < 4; lt++) {
      f4v sacc[4];
#pragma unroll
      for (int j = 0; j < 4; j++)
#pragma unroll
        for (int r = 0; r < 4; r++) sacc[j][r] = 0.f;
#pragma unroll
      for (int ks = 0; ks < 4; ks++)
#pragma unroll
        for (int j = 0; j < 4; j++)
          sacc[j] = mfma_bf16(cfr[lt][ks],
              *(const s8v*)&B_s[j * 16 + lr][ks * 32 + q * 8], sacc[j]);
      int lbase = lt * 64 + wl0 + q * 4;
#pragma unroll
      for (int j = 0; j < 4; j++) {
        int sg = st * 64 + j * 16 + lr;
#pragma unroll
        for (int r = 0; r < 4; r++) {
          int ll = lbase + r;
          float m = (sg <= ll) ? sacc[j][r] * __expf(Acum[ll] - Acum[sg]) : 0.f;
          Mt[wl0 + q * 4 + r][j * 16 + lr] = f2bf(m);
        }
      }
      __syncthreads();   // publish Mt (wave-stripe; conservative)
#pragma unroll
      for (int ss2 = 0; ss2 < 2; ss2++) {
        s8v a = *(const s8v*)&Mt[wl0 + lr][ss2 * 32 + q * 8];
#pragma unroll
        for (int j = 0; j < 4; j++)
          acc[lt][j] = mfma_bf16(a,
              *(const s8v*)&xdtT[j * 16 + lr][ss2 * 32 + q * 8], acc[lt][j]);
      }
    }
    __syncthreads();   // WAR: B_s/xdtT (and Mt) reads done before next st
  }

  // epilogue: fold D*x, transpose via Mt (wave-own rows), coalesced store
  for (int lt = 0; lt < 4; lt++) {
#pragma unroll
    for (int j = 0; j < 4; j++)
#pragma unroll
      for (int r = 0; r < 4; r++) {
        int lrow = wl0 + q * 4 + r;
        int ll = lt * 64 + lrow;
        int p = j * 16 + lr;
        float xv = bf2f(xBCc[(row0 + ll) * CONVD + h * PDIM + p]);
        Mt[lrow][p] = f2bf(acc[lt][j][r] + Dh * xv);
      }
    __syncthreads();
#pragma unroll
    for (int ps = 0; ps < 2; ps++) {
      int r = ps * 32 + (tid >> 3);
      int c8 = (tid & 7) * 8;
      s8v v = *(const s8v*)&Mt[r][c8];
      *(s8v*)&y[(row0 + lt * 64 + r) * DINNER + h * PDIM + c8] = v;
    }
    __syncthreads();   // WAR before next lt's Mt write
  }
}

// ------------------- gated RMSNorm -> bf16, + folded W_out cast ----------
// blocks [0,4096): norm rows; blocks [4096,6144): cast W_out fp32->bf16
// (wout region aliases `states`, dead by now; could NOT cast earlier since
// it also aliases win_bf during gemm1).
__global__ __launch_bounds__(256) void norm_cast_kernel(
    const short* __restrict__ y, const short* __restrict__ z,
    const float* __restrict__ norm_w, short* __restrict__ g,
    const float* __restrict__ wsrc, short* __restrict__ wdst) {
  int bl = blockIdx.x, tid = threadIdx.x;
  if (bl >= 4096) {
    int base = (bl - 4096) * 1024 + tid;
#pragma unroll
    for (int i = 0; i < 4; i++) {
      int idx = base + i * 256;
      float4 v = ((const float4*)wsrc)[idx];
      short4 o;
      o.x = f2bf(v.x); o.y = f2bf(v.y); o.z = f2bf(v.z); o.w = f2bf(v.w);
      ((short4*)wdst)[idx] = o;
    }
    return;
  }
  const short4* yrow = (const short4*)(y + (size_t)bl * DINNER);
  const short4* zrow = (const short4*)(z + (size_t)bl * DINNER);
  float gv[16];
  float ss = 0.f;
  for (int i = 0; i < 4; i++) {
    short4 yv = yrow[tid + i * 256];
    short4 zv = zrow[tid + i * 256];
    float zf[4] = {bf2f(zv.x), bf2f(zv.y), bf2f(zv.z), bf2f(zv.w)};
    float yf[4] = {bf2f(yv.x), bf2f(yv.y), bf2f(yv.z), bf2f(yv.w)};
    for (int t = 0; t < 4; t++) {
      float gg = yf[t] * (zf[t] / (1.f + expf(-zf[t])));
      gv[i * 4 + t] = gg;
      ss += gg * gg;
    }
  }
  for (int off = 32; off > 0; off >>= 1) ss += __shfl_down(ss, off);
  __shared__ float red[4];
  __shared__ float rsS;
  if ((tid & 63) == 0) red[tid >> 6] = ss;
  __syncthreads();
  if (tid == 0) rsS = rsqrtf((red[0] + red[1] + red[2] + red[3]) * (1.f / 4096.f) + 1e-5f);
  __syncthreads();
  float rs = rsS;
  for (int i = 0; i < 4; i++) {
    int j4 = (tid + i * 256) * 4;
    float4 nw = *(const float4*)&norm_w[j4];
    short4 o;
    o.x = f2bf(gv[i * 4 + 0] * rs * nw.x);
    o.y = f2bf(gv[i * 4 + 1] * rs * nw.y);
    o.z = f2bf(gv[i * 4 + 2] * rs * nw.z);
    o.w = f2bf(gv[i * 4 + 3] * rs * nw.w);
    *(short4*)&g[(size_t)bl * DINNER + j4] = o;
  }
}

extern "C" void kernel_launch(void* const* d_in, const int* in_sizes, int n_in,
                              void* d_out, int out_size, void* d_ws, size_t ws_size,
                              hipStream_t stream) {
  const float* hidden  = (const float*)d_in[0];
  const float* W_in    = (const float*)d_in[1];
  const float* conv_w  = (const float*)d_in[2];
  const float* conv_b  = (const float*)d_in[3];
  const float* dt_bias = (const float*)d_in[4];
  const float* A_log   = (const float*)d_in[5];
  const float* D_param = (const float*)d_in[6];
  const float* norm_w  = (const float*)d_in[7];
  const float* W_out   = (const float*)d_in[8];
  float* out = (float*)d_out;

  // ---- workspace arena (122,687,488 bytes), phase-overlapped regions ----
  char* ws = (char*)d_ws;
  short* z_bf  = (short*)(ws + 0);                     // 33,554,432
  float* dtb   = (float*)(ws + 33554432);              //  1,048,576
  float* da_l  = (float*)(ws + 34603008);              //  4 KB
  short* xbc_pre = (short*)(ws + 34607104);            // 35,651,584 (GEMM1->conv)
  short* y_bf    = (short*)(ws + 34607104);            // 33,554,432 (ssd_y->norm)
  short* hid_bf  = (short*)(ws + 70258688);            // 16,777,216 (casts->GEMM1)
  short* win_bf  = (short*)(ws + 87035904);            // 34,865,152 (casts->GEMM1)
  short* xBCc    = (short*)(ws + 70258688);            // 35,651,584 (conv->ssd)
  short* states  = (short*)(ws + 105910272);           // 16,777,216 (ssd)
  short* g_bf    = (short*)(ws + 70258688);            // 33,554,432 (norm->GEMM2)
  short* wout_bf = (short*)(ws + 105910272);           // 16,777,216 (cast->GEMM2)
  if (ws_size < (size_t)122687488) return;

  cast_bf16_kernel<<<8192, 256, 0, stream>>>(hidden, hid_bf, 2097152);
  cast_bf16_kernel<<<17024, 256, 0, stream>>>(W_in, win_bf, 4358144);

  gemm1_256<<<544, 512, 0, stream>>>(hid_bf, win_bf, z_bf, xbc_pre, dtb);

  conv_silu_kernel<<<dim3(17, 4096), 256, 0, stream>>>(xbc_pre, conv_w, conv_b, xBCc);
  dt_kernel<<<1024, 256, 0, stream>>>(dtb, dt_bias);

  ssd_states_kernel<<<1024, 256, 0, stream>>>(xBCc, dtb, A_log, states, da_l);
  scan_kernel<<<512, 256, 0, stream>>>(states, da_l);
  ssd_y_kernel<<<1024, 256, 0, stream>>>(xBCc, dtb, A_log, D_param, states, y_bf);

  norm_cast_kernel<<<6144, 256, 0, stream>>>(y_bf, z_bf, norm_w, g_bf, W_out, wout_bf);

  gemm2_256x128<<<256, 512, 0, stream>>>(g_bf, wout_bf, out);
}

// Round 8
// 647.618 us; speedup vs baseline: 1.1027x; 1.1027x over previous
//
#include <hip/hip_runtime.h>

#define SEQLEN 2048
#define NHEADS 64
#define PDIM 64
#define NSTATE 128
#define CSIZE 256
#define NCHUNK 8
#define DINNER 4096
#define CONVD 4352
#define PROJD 8512

using s8v = __attribute__((ext_vector_type(8))) short;
using f4v = __attribute__((ext_vector_type(4))) float;
using bf8v = __attribute__((ext_vector_type(8))) __bf16;

__device__ __forceinline__ short f2bf(float x) {
  union { float f; unsigned u; } t; t.f = x;
  unsigned r = t.u + 0x7FFFu + ((t.u >> 16) & 1u);
  return (short)(r >> 16);
}
__device__ __forceinline__ float bf2f(short s) {
  union { unsigned u; float f; } t;
  t.u = ((unsigned)(unsigned short)s) << 16;
  return t.f;
}

__device__ __forceinline__ f4v mfma_bf16(s8v a, s8v b, f4v c) {
  return __builtin_amdgcn_mfma_f32_16x16x32_bf16(
      __builtin_bit_cast(bf8v, a), __builtin_bit_cast(bf8v, b), c, 0, 0, 0);
}

// async global->LDS, 16B per lane; LDS dest must be lane-contiguous
__device__ __forceinline__ void gll16(const void* g, void* l) {
  __builtin_amdgcn_global_load_lds(
      (const __attribute__((address_space(1))) unsigned*)g,
      (__attribute__((address_space(3))) unsigned*)l, 16, 0, 0);
}

// ---------------------------------------------------------------- casts
__global__ __launch_bounds__(256) void cast_bf16_kernel(
    const float* __restrict__ in, short* __restrict__ out, int n4) {
  int i = blockIdx.x * 256 + threadIdx.x;
  if (i < n4) {
    float4 v = ((const float4*)in)[i];
    short4 o;
    o.x = f2bf(v.x); o.y = f2bf(v.y); o.z = f2bf(v.z); o.w = f2bf(v.w);
    ((short4*)out)[i] = o;
  }
}

// ===================== GEMM1: 256x256 8-phase pipelined (m201 template) ====
// FROZEN at the r1/r2/r6-measured form (182-184us, MfmaUtil 33.4). The
// dt_bias+softplus epilogue fusion poisoned the K-loop codegen (r3-r5 all
// ~239us); any edit to this kernel needs a full A/B. Do not touch.

#define G1_STAGE_A(dst, h, kt) do {                                          \
    _Pragma("unroll")                                                        \
    for (int it_ = 0; it_ < 2; ++it_) {                                      \
      int ci_ = it_ * 512 + tid;                                             \
      int r_ = ci_ >> 3;                                                     \
      int g_ = ((ci_ & 7) ^ (r_ & 7)) << 3;                                  \
      gll16(&A[(size_t)(tm0 + (h) * 128 + r_) * 2048 + (kt) * 64 + g_],      \
            &(dst)[(h) * 8192 + ci_ * 8]);                                   \
    }                                                                        \
  } while (0)

#define G1_STAGE_B(dst, h, kt) do {                                          \
    _Pragma("unroll")                                                        \
    for (int it_ = 0; it_ < 2; ++it_) {                                      \
      int ci_ = it_ * 512 + tid;                                             \
      int r_ = ci_ >> 3;                                                     \
      int g_ = ((ci_ & 7) ^ (r_ & 7)) << 3;                                  \
      int br_ = tn0 + (h) * 128 + r_;                                        \
      if (br_ > 8511) br_ = 8511; /* dt-strip tile over-reads: clamp */      \
      gll16(&B[(size_t)br_ * 2048 + (kt) * 64 + g_],                         \
            &(dst)[(h) * 8192 + ci_ * 8]);                                   \
    }                                                                        \
  } while (0)

#define RD_A(m, ks) \
  (*(const s8v*)&Ad[(wm + (m) * 16 + lr) * 64 + (((ks) * 4 + q) ^ sw7) * 8])
#define RD_B(n, ks) \
  (*(const s8v*)&Bd[(wn + (n) * 16 + lr) * 64 + (((ks) * 4 + q) ^ sw7) * 8])

#define G1_MFMA2(m0, x00, x01, x10, x11) do {                                \
    __builtin_amdgcn_s_setprio(1);                                           \
    _Pragma("unroll") for (int n = 0; n < 4; ++n)                            \
      acc[m0][n] = mfma_bf16(x00, bk0[n], acc[m0][n]);                       \
    _Pragma("unroll") for (int n = 0; n < 4; ++n)                            \
      acc[m0][n] = mfma_bf16(x01, bk1[n], acc[m0][n]);                       \
    _Pragma("unroll") for (int n = 0; n < 4; ++n)                            \
      acc[(m0) + 1][n] = mfma_bf16(x10, bk0[n], acc[(m0) + 1][n]);           \
    _Pragma("unroll") for (int n = 0; n < 4; ++n)                            \
      acc[(m0) + 1][n] = mfma_bf16(x11, bk1[n], acc[(m0) + 1][n]);           \
    __builtin_amdgcn_s_setprio(0);                                           \
  } while (0)

__global__ __launch_bounds__(512, 2) void gemm1_256(
    const short* __restrict__ A, const short* __restrict__ B,
    short* __restrict__ z, short* __restrict__ xbc, float* __restrict__ dtb) {
  const int NT = 32;  // 2048 / 64
  // XCD-bijective swizzle (544 % 8 == 0) then 4-high panel map for L2 reuse
  const int bid = blockIdx.x;
  const int sid = (bid & 7) * 68 + (bid >> 3);
  const int panel = sid / 136, rem = sid % 136;
  const int bx = rem >> 2, by = panel * 4 + (rem & 3);
  const int tm0 = by * 256, tn0 = bx * 256;
  __shared__ alignas(16) short lds[65536];  // 128 KB
  const int tid = threadIdx.x;
  const int lane = tid & 63, wid = tid >> 6;
  const int wm = (wid >> 2) * 128, wn = (wid & 3) * 64;
  const int lr = lane & 15, q = lane >> 4;
  const int sw7 = lr & 7;

  f4v acc[8][4];
#pragma unroll
  for (int m = 0; m < 8; ++m)
#pragma unroll
    for (int n = 0; n < 4; ++n)
#pragma unroll
      for (int r = 0; r < 4; ++r) acc[m][n][r] = 0.f;

  // prologue: tile0 {Ah0,Ah1,Bh0,Bh1}, tile1 {Bh0,Bh1}  (12 loads/thread)
  {
    short* A0 = lds;
    short* B0 = lds + 16384;
    short* B1 = lds + 49152;
    G1_STAGE_A(A0, 0, 0); G1_STAGE_A(A0, 1, 0);
    G1_STAGE_B(B0, 0, 0); G1_STAGE_B(B0, 1, 0);
    G1_STAGE_B(B1, 0, 1); G1_STAGE_B(B1, 1, 1);
    // drain A(0),B(0); leave B(1) in flight
    asm volatile("s_waitcnt vmcnt(4)" ::: "memory");
    __builtin_amdgcn_s_barrier();
  }

  for (int t = 0; t < NT; ++t) {
    short* Ad = lds + ((t & 1) << 15);
    short* Bd = Ad + 16384;
    short* An = lds + (((t + 1) & 1) << 15);
    s8v bk0[4], bk1[4];
    // ---- p0: all B-frags + a0,a1; stage Ah0(t+1)
    {
#pragma unroll
      for (int n = 0; n < 4; ++n) { bk0[n] = RD_B(n, 0); bk1[n] = RD_B(n, 1); }
      s8v a00 = RD_A(0, 0), a01 = RD_A(0, 1);
      s8v a10 = RD_A(1, 0), a11 = RD_A(1, 1);
      if (t + 1 < NT) G1_STAGE_A(An, 0, t + 1);
      __builtin_amdgcn_s_barrier();
      asm volatile("s_waitcnt lgkmcnt(0)" ::: "memory");
      G1_MFMA2(0, a00, a01, a10, a11);
      __builtin_amdgcn_s_barrier();
    }
    // ---- p1
    {
      s8v a00 = RD_A(2, 0), a01 = RD_A(2, 1);
      s8v a10 = RD_A(3, 0), a11 = RD_A(3, 1);
      if (t + 1 < NT) G1_STAGE_A(An, 1, t + 1);
      __builtin_amdgcn_s_barrier();
      asm volatile("s_waitcnt lgkmcnt(0)" ::: "memory");
      G1_MFMA2(2, a00, a01, a10, a11);
      __builtin_amdgcn_s_barrier();
    }
    // ---- p2: B(t+2) h0 into CURRENT B region (dead after p0 reads)
    {
      s8v a00 = RD_A(4, 0), a01 = RD_A(4, 1);
      s8v a10 = RD_A(5, 0), a11 = RD_A(5, 1);
      if (t + 2 < NT) G1_STAGE_B(Bd, 0, t + 2);
      __builtin_amdgcn_s_barrier();
      asm volatile("s_waitcnt lgkmcnt(0)" ::: "memory");
      G1_MFMA2(4, a00, a01, a10, a11);
      __builtin_amdgcn_s_barrier();
    }
    // ---- p3: counted vmcnt validates tile t+1 for p0(t+1)'s reads
    {
      s8v a00 = RD_A(6, 0), a01 = RD_A(6, 1);
      s8v a10 = RD_A(7, 0), a11 = RD_A(7, 1);
      if (t + 2 < NT) G1_STAGE_B(Bd, 1, t + 2);
      if (t < NT - 2) {
        asm volatile("s_waitcnt vmcnt(4)" ::: "memory");
      } else {
        asm volatile("s_waitcnt vmcnt(0)" ::: "memory");
      }
      __builtin_amdgcn_s_barrier();
      asm volatile("s_waitcnt lgkmcnt(0)" ::: "memory");
      G1_MFMA2(6, a00, a01, a10, a11);
      __builtin_amdgcn_s_barrier();
    }
  }

  // ------------------------------ epilogue ------------------------------
  if (bx == 33) {  // dt strip: cols 8448..8511, fp32, wn==0 waves hold them
    if (wn == 0) {
#pragma unroll
      for (int m = 0; m < 8; ++m)
#pragma unroll
        for (int n = 0; n < 4; ++n) {
          int col = n * 16 + lr;
#pragma unroll
          for (int r = 0; r < 4; ++r) {
            int row = tm0 + wm + m * 16 + q * 4 + r;
            dtb[(size_t)row * NHEADS + col] = acc[m][n][r];
          }
        }
    }
    return;
  }
  short* outp; int stride, colbase;
  if (bx < 16) { outp = z;   stride = DINNER; colbase = tn0; }
  else         { outp = xbc; stride = CONVD;  colbase = tn0 - DINNER; }
  short* Cs = lds;  // [128][264] bf16 staging, all pipeline work drained
  for (int h = 0; h < 2; ++h) {
    __syncthreads();
    if ((wid >> 2) == h) {
#pragma unroll
      for (int m = 0; m < 8; ++m)
#pragma unroll
        for (int n = 0; n < 4; ++n)
#pragma unroll
          for (int r = 0; r < 4; ++r)
            Cs[(m * 16 + q * 4 + r) * 264 + wn + n * 16 + lr] =
                f2bf(acc[m][n][r]);
    }
    __syncthreads();
#pragma unroll
    for (int itr = 0; itr < 8; ++itr) {
      int idx = itr * 512 + tid;
      int r = idx >> 5, c8 = (idx & 31) * 8;
      s8v v = *(const s8v*)&Cs[r * 264 + c8];
      *(s8v*)&outp[(size_t)(tm0 + h * 128 + r) * stride + colbase + c8] = v;
    }
  }
}

// ======== GEMM2: 256x128-tile 8-phase, grid 256 = EXACTLY 1 round =========
// out = g @ W_out^T. M=4096, N=2048, K=4096. Block 512 thr (8 waves 2Mx4N,
// per-wave out 128x32). LDS 96KB: buf[2] x { A[256][64], B[128][64] }.

#define G2_STAGE_A(dst, h, kt) do {                                          \
    _Pragma("unroll")                                                        \
    for (int it_ = 0; it_ < 2; ++it_) {                                      \
      int ci_ = it_ * 512 + tid;                                             \
      int r_ = ci_ >> 3;                                                     \
      int g_ = ((ci_ & 7) ^ (r_ & 7)) << 3;                                  \
      gll16(&Ag[(size_t)(tm0 + (h) * 128 + r_) * 4096 + (kt) * 64 + g_],     \
            &(dst)[(h) * 8192 + ci_ * 8]);                                   \
    }                                                                        \
  } while (0)

#define G2_STAGE_B(dst, h, kt) do {                                          \
    int ci_ = tid;                                                           \
    int r_ = ci_ >> 3;                                                       \
    int g_ = ((ci_ & 7) ^ (r_ & 7)) << 3;                                    \
    gll16(&Bg[(size_t)(tn0 + (h) * 64 + r_) * 4096 + (kt) * 64 + g_],        \
          &(dst)[(h) * 4096 + ci_ * 8]);                                     \
  } while (0)

#define RD_A2(m, ks) \
  (*(const s8v*)&Ad[(wm + (m) * 16 + lr) * 64 + (((ks) * 4 + q) ^ sw7) * 8])
#define RD_B2(n, ks) \
  (*(const s8v*)&Bd[(wn + (n) * 16 + lr) * 64 + (((ks) * 4 + q) ^ sw7) * 8])

#define G2_MFMA2(m0, x00, x01, x10, x11) do {                                \
    __builtin_amdgcn_s_setprio(1);                                           \
    _Pragma("unroll") for (int n = 0; n < 2; ++n)                            \
      acc[m0][n] = mfma_bf16(x00, bk0[n], acc[m0][n]);                       \
    _Pragma("unroll") for (int n = 0; n < 2; ++n)                            \
      acc[m0][n] = mfma_bf16(x01, bk1[n], acc[m0][n]);                       \
    _Pragma("unroll") for (int n = 0; n < 2; ++n)                            \
      acc[(m0) + 1][n] = mfma_bf16(x10, bk0[n], acc[(m0) + 1][n]);           \
    _Pragma("unroll") for (int n = 0; n < 2; ++n)                            \
      acc[(m0) + 1][n] = mfma_bf16(x11, bk1[n], acc[(m0) + 1][n]);           \
    __builtin_amdgcn_s_setprio(0);                                           \
  } while (0)

__global__ __launch_bounds__(512, 2) void gemm2_256x128(
    const short* __restrict__ Ag, const short* __restrict__ Bg,
    float* __restrict__ C) {
  const int NT = 64;  // 4096 / 64
  // XCD-bijective swizzle (256 % 8 == 0), 4-high panels
  const int bid = blockIdx.x;
  const int sid = (bid & 7) * 32 + (bid >> 3);
  const int panel = sid >> 6, rem = sid & 63;
  const int bx = rem >> 2, by = panel * 4 + (rem & 3);
  const int tm0 = by * 256, tn0 = bx * 128;
  __shared__ alignas(16) short lds[49152];  // 96 KB
  const int tid = threadIdx.x;
  const int lane = tid & 63, wid = tid >> 6;
  const int wm = (wid >> 2) * 128, wn = (wid & 3) * 32;
  const int lr = lane & 15, q = lane >> 4;
  const int sw7 = lr & 7;

  f4v acc[8][2];
#pragma unroll
  for (int m = 0; m < 8; ++m)
#pragma unroll
    for (int n = 0; n < 2; ++n)
#pragma unroll
      for (int r = 0; r < 4; ++r) acc[m][n][r] = 0.f;

  // prologue: A0 h0,h1 (4) + B0 h0,h1 (2) + B1 h0,h1 (2)
  {
    short* A0 = lds;
    short* B0 = lds + 16384;
    short* B1 = lds + 40960;
    G2_STAGE_A(A0, 0, 0); G2_STAGE_A(A0, 1, 0);
    G2_STAGE_B(B0, 0, 0); G2_STAGE_B(B0, 1, 0);
    G2_STAGE_B(B1, 0, 1); G2_STAGE_B(B1, 1, 1);
    asm volatile("s_waitcnt vmcnt(2)" ::: "memory");  // leave B(1) in flight
    __builtin_amdgcn_s_barrier();
  }

  for (int t = 0; t < NT; ++t) {
    short* Ad = lds + (t & 1) * 24576;
    short* Bd = Ad + 16384;
    short* An = lds + ((t + 1) & 1) * 24576;
    s8v bk0[2], bk1[2];
    // ---- p0
    {
#pragma unroll
      for (int n = 0; n < 2; ++n) { bk0[n] = RD_B2(n, 0); bk1[n] = RD_B2(n, 1); }
      s8v a00 = RD_A2(0, 0), a01 = RD_A2(0, 1);
      s8v a10 = RD_A2(1, 0), a11 = RD_A2(1, 1);
      if (t + 1 < NT) G2_STAGE_A(An, 0, t + 1);
      __builtin_amdgcn_s_barrier();
      asm volatile("s_waitcnt lgkmcnt(0)" ::: "memory");
      G2_MFMA2(0, a00, a01, a10, a11);
      __builtin_amdgcn_s_barrier();
    }
    // ---- p1
    {
      s8v a00 = RD_A2(2, 0), a01 = RD_A2(2, 1);
      s8v a10 = RD_A2(3, 0), a11 = RD_A2(3, 1);
      if (t + 1 < NT) G2_STAGE_A(An, 1, t + 1);
      __builtin_amdgcn_s_barrier();
      asm volatile("s_waitcnt lgkmcnt(0)" ::: "memory");
      G2_MFMA2(2, a00, a01, a10, a11);
      __builtin_amdgcn_s_barrier();
    }
    // ---- p2: B(t+2) h0 into CURRENT B region (dead after p0 reads)
    {
      s8v a00 = RD_A2(4, 0), a01 = RD_A2(4, 1);
      s8v a10 = RD_A2(5, 0), a11 = RD_A2(5, 1);
      if (t + 2 < NT) G2_STAGE_B(Bd, 0, t + 2);
      __builtin_amdgcn_s_barrier();
      asm volatile("s_waitcnt lgkmcnt(0)" ::: "memory");
      G2_MFMA2(4, a00, a01, a10, a11);
      __builtin_amdgcn_s_barrier();
    }
    // ---- p3: counted vmcnt validates tile t+1
    {
      s8v a00 = RD_A2(6, 0), a01 = RD_A2(6, 1);
      s8v a10 = RD_A2(7, 0), a11 = RD_A2(7, 1);
      if (t + 2 < NT) G2_STAGE_B(Bd, 1, t + 2);
      if (t < NT - 2) {
        asm volatile("s_waitcnt vmcnt(2)" ::: "memory");
      } else {
        asm volatile("s_waitcnt vmcnt(0)" ::: "memory");
      }
      __builtin_amdgcn_s_barrier();
      asm volatile("s_waitcnt lgkmcnt(0)" ::: "memory");
      G2_MFMA2(6, a00, a01, a10, a11);
      __builtin_amdgcn_s_barrier();
    }
  }

  // epilogue: fp32 dword scatter (64B/quarter-wave segments)
#pragma unroll
  for (int m = 0; m < 8; ++m)
#pragma unroll
    for (int n = 0; n < 2; ++n) {
      int r0 = tm0 + wm + m * 16 + q * 4;
      int c0 = tn0 + wn + n * 16 + lr;
#pragma unroll
      for (int r = 0; r < 4; ++r)
        C[(size_t)(r0 + r) * 2048 + c0] = acc[m][n][r];
    }
}

// ------------------------------------------------ depthwise conv + SiLU
__global__ __launch_bounds__(256) void conv_silu_kernel(
    const short* __restrict__ xbc, const float* __restrict__ conv_w,
    const float* __restrict__ conv_b, short* __restrict__ xBCc) {
  int cc = blockIdx.x * 256 + threadIdx.x;  // 0..4351
  int bl = blockIdx.y;
  int b = bl >> 11, l = bl & 2047;
  float4 wv = *(const float4*)&conv_w[cc * 4];
  float wk[4] = {wv.x, wv.y, wv.z, wv.w};
  float acc = conv_b[cc];
  const short* pbase = xbc + (size_t)(b * SEQLEN) * CONVD + cc;
#pragma unroll
  for (int k = 0; k < 4; k++) {
    int ls = l - 3 + k;
    if (ls >= 0) acc += bf2f(pbase[(size_t)ls * CONVD]) * wk[k];
  }
  float sv = acc / (1.f + expf(-acc));
  xBCc[(size_t)bl * CONVD + cc] = f2bf(sv);
}

// ----------------------------------------------------- dt softplus (in-place)
__global__ __launch_bounds__(256) void dt_kernel(
    float* __restrict__ dtb, const float* __restrict__ dt_bias) {
  int idx = blockIdx.x * 256 + threadIdx.x;  // < 4096*64
  int hh = idx & 63;
  float v = dtb[idx] + dt_bias[hh];
  dtb[idx] = (v > 20.f) ? v : log1pf(expf(v));
}

// ---------------------------------------- per-chunk states (fp32 VALU)
__global__ __launch_bounds__(256) void ssd_states_kernel(
    const short* __restrict__ xBCc, const float* __restrict__ dtp,
    const float* __restrict__ A_log, short* __restrict__ states,
    float* __restrict__ da_last) {
  const int blk = blockIdx.x;
  const int h = blk & 63, cc = (blk >> 6) & 7, b = blk >> 9;
  const int tid = threadIdx.x;
  __shared__ float dt_s[CSIZE], Acum[CSIZE], w_s[CSIZE];
  __shared__ float xw[64][64];
  __shared__ float Bt[64][NSTATE];
  const size_t row0 = (size_t)(b * SEQLEN + cc * CSIZE);
  dt_s[tid] = dtp[(row0 + tid) * NHEADS + h];
  __syncthreads();
  if (tid == 0) {
    float Aval = -expf(A_log[h]);
    float s = 0.f;
    for (int i = 0; i < CSIZE; i++) { s += dt_s[i]; Acum[i] = s * Aval; }
    da_last[(size_t)(b * NHEADS + h) * NCHUNK + cc] = Acum[CSIZE - 1];
  }
  __syncthreads();
  float total = Acum[CSIZE - 1];
  w_s[tid] = dt_s[tid] * expf(total - Acum[tid]);
  float acc[4][8];
  for (int a = 0; a < 4; a++) for (int j = 0; j < 8; j++) acc[a][j] = 0.f;
  const int pi = (tid & 15) * 4, ni = (tid >> 4) * 8;
  for (int lt = 0; lt < 4; lt++) {
    __syncthreads();
    for (int i = 0; i < 4; i++) {
      int idx = tid + i * 256;
      int r = idx >> 4, c4 = (idx & 15) << 2;
      short4 v = *(const short4*)&xBCc[(row0 + lt * 64 + r) * CONVD + h * PDIM + c4];
      float wl = w_s[lt * 64 + r];
      xw[r][c4 + 0] = bf2f(v.x) * wl;
      xw[r][c4 + 1] = bf2f(v.y) * wl;
      xw[r][c4 + 2] = bf2f(v.z) * wl;
      xw[r][c4 + 3] = bf2f(v.w) * wl;
    }
    for (int i = 0; i < 8; i++) {
      int idx = tid + i * 256;
      int r = idx >> 5, c4 = (idx & 31) << 2;
      short4 v = *(const short4*)&xBCc[(row0 + lt * 64 + r) * CONVD + DINNER + c4];
      Bt[r][c4 + 0] = bf2f(v.x);
      Bt[r][c4 + 1] = bf2f(v.y);
      Bt[r][c4 + 2] = bf2f(v.z);
      Bt[r][c4 + 3] = bf2f(v.w);
    }
    __syncthreads();
    for (int l = 0; l < 64; l++) {
      float4 xv = *(const float4*)&xw[l][pi];
      float4 b0 = *(const float4*)&Bt[l][ni];
      float4 b1 = *(const float4*)&Bt[l][ni + 4];
      float xa[4] = {xv.x, xv.y, xv.z, xv.w};
      float bb[8] = {b0.x, b0.y, b0.z, b0.w, b1.x, b1.y, b1.z, b1.w};
      for (int a = 0; a < 4; a++)
        for (int j = 0; j < 8; j++)
          acc[a][j] += xa[a] * bb[j];
    }
  }
  const size_t sbase = (((size_t)b * NCHUNK + cc) * NHEADS + h) * (PDIM * NSTATE);
  for (int a = 0; a < 4; a++) {
    short o[8];
    for (int j = 0; j < 8; j++) o[j] = f2bf(acc[a][j]);
    *(s8v*)&states[sbase + (size_t)(pi + a) * NSTATE + ni] = *(const s8v*)o;
  }
}

// ---------------- 8-step chunk scan (in-place, s8v vectorized) -----------
__global__ __launch_bounds__(256) void scan_kernel(
    short* __restrict__ states, const float* __restrict__ da_last) {
  const int bh = blockIdx.x >> 2, sl = blockIdx.x & 3;
  const int b = bh >> 6, h = bh & 63;
  const int tid = threadIdx.x;
  float prev[8];
#pragma unroll
  for (int i = 0; i < 8; i++) prev[i] = 0.f;
  for (int c = 0; c < NCHUNK; c++) {
    const size_t base = (((size_t)b * NCHUNK + c) * NHEADS + h) * (PDIM * NSTATE)
                      + sl * 2048;
    const float d = expf(da_last[(size_t)bh * NCHUNK + c]);
    size_t e0 = base + (size_t)tid * 8;
    s8v sv = *(const s8v*)&states[e0];
    short ov[8];
#pragma unroll
    for (int i = 0; i < 8; i++) {
      float s = bf2f(sv[i]);
      ov[i] = f2bf(prev[i]);
      prev[i] = prev[i] * d + s;
    }
    *(s8v*)&states[e0] = *(const s8v*)ov;
  }
}

// ----- SSD Y v3: st-outer with FULLY STATIC indexing (rule-#20 fix) ------
// v2 regressed (r7: +70us): `for (lt = st; ...)` runtime bounds + unpragma'd
// epilogue loop demoted acc[4][4]/cfr[4][4] to scratch. v3: every loop
// touching acc/cfr is #pragma unroll with static 0..4 bounds; causal guard
// is `if (lt >= st)` which resolves at compile time after double unroll.
__global__ __launch_bounds__(256) void ssd_y_kernel(
    const short* __restrict__ xBCc, const float* __restrict__ dtp,
    const float* __restrict__ A_log, const float* __restrict__ D_param,
    const short* __restrict__ prevs, short* __restrict__ y) {
  const int blk = blockIdx.x;
  const int h = blk & 63, cc = (blk >> 6) & 7, b = blk >> 9;
  const int tid = threadIdx.x;
  const int lane = tid & 63, w = tid >> 6;
  const int lr = lane & 15, q = lane >> 4;
  __shared__ float dt_s[CSIZE];
  __shared__ float Acum[CSIZE];
  __shared__ short PV_s[64][136];   // prev state tile (staged once)
  __shared__ short B_s[64][136];    // B[st] tile (staged per st)
  __shared__ short xdtT[64][72];    // (x*dt)^T [p][l] (staged per st)
  __shared__ short Mt[64][72];      // masked-score / epilogue transpose buf
  const size_t row0 = (size_t)(b * SEQLEN + cc * CSIZE);
  dt_s[tid] = dtp[(row0 + tid) * NHEADS + h];
  __syncthreads();
  if (tid == 0) {
    float Aval = -expf(A_log[h]);
    float s = 0.f;
    for (int i = 0; i < CSIZE; i++) { s += dt_s[i]; Acum[i] = s * Aval; }
  }
  const float Dh = D_param[h];
  const size_t prevbase = (((size_t)b * NCHUNK + cc) * NHEADS + h) * (PDIM * NSTATE);
  const int wl0 = w * 16;

  // stage prev once (concurrent with tid0's Acum fill; barrier publishes both)
#pragma unroll
  for (int i = 0; i < 4; i++) {
    int idx = tid + i * 256;
    int r = idx >> 4, c8 = (idx & 15) << 3;
    *(s8v*)&PV_s[r][c8] = *(const s8v*)&prevs[prevbase + (size_t)r * NSTATE + c8];
  }
  __syncthreads();

  // C-fragments direct from global (L2-hot) + phase A: acc[lt] = C @ prev^T
  s8v cfr[4][4];
  f4v acc[4][4];
#pragma unroll
  for (int lt = 0; lt < 4; lt++) {
#pragma unroll
    for (int ks = 0; ks < 4; ks++)
      cfr[lt][ks] = *(const s8v*)&xBCc[(row0 + lt * 64 + wl0 + lr) * CONVD
                                       + DINNER + NSTATE + ks * 32 + q * 8];
#pragma unroll
    for (int j = 0; j < 4; j++)
#pragma unroll
      for (int r = 0; r < 4; r++) acc[lt][j][r] = 0.f;
#pragma unroll
    for (int ks = 0; ks < 4; ks++)
#pragma unroll
      for (int j = 0; j < 4; j++)
        acc[lt][j] = mfma_bf16(cfr[lt][ks],
            *(const s8v*)&PV_s[j * 16 + lr][ks * 32 + q * 8], acc[lt][j]);
#pragma unroll
    for (int r = 0; r < 4; r++) {
      float e = __expf(Acum[lt * 64 + wl0 + q * 4 + r]);
#pragma unroll
      for (int j = 0; j < 4; j++) acc[lt][j][r] *= e;
    }
  }

  // phase B: st-outer — stage B[st] + xdt[st] once, sweep lt >= st (static)
#pragma unroll
  for (int st = 0; st < 4; st++) {
#pragma unroll
    for (int i = 0; i < 4; i++) {
      int idx = tid + i * 256;
      int r = idx >> 4, c8 = (idx & 15) << 3;
      *(s8v*)&B_s[r][c8] =
          *(const s8v*)&xBCc[(row0 + st * 64 + r) * CONVD + DINNER + c8];
    }
#pragma unroll
    for (int i = 0; i < 4; i++) {
      int idx = tid + i * 256;
      int r = idx >> 4, c4 = (idx & 15) << 2;
      float dtv = dt_s[st * 64 + r];
      short4 v = *(const short4*)&xBCc[(row0 + st * 64 + r) * CONVD + h * PDIM + c4];
      xdtT[c4 + 0][r] = f2bf(bf2f(v.x) * dtv);
      xdtT[c4 + 1][r] = f2bf(bf2f(v.y) * dtv);
      xdtT[c4 + 2][r] = f2bf(bf2f(v.z) * dtv);
      xdtT[c4 + 3][r] = f2bf(bf2f(v.w) * dtv);
    }
    __syncthreads();
#pragma unroll
    for (int lt = 0; lt < 4; lt++) {
      if (lt >= st) {   // compile-time after unroll; block-uniform
        f4v sacc[4];
#pragma unroll
        for (int j = 0; j < 4; j++)
#pragma unroll
          for (int r = 0; r < 4; r++) sacc[j][r] = 0.f;
#pragma unroll
        for (int ks = 0; ks < 4; ks++)
#pragma unroll
          for (int j = 0; j < 4; j++)
            sacc[j] = mfma_bf16(cfr[lt][ks],
                *(const s8v*)&B_s[j * 16 + lr][ks * 32 + q * 8], sacc[j]);
        int lbase = lt * 64 + wl0 + q * 4;
#pragma unroll
        for (int j = 0; j < 4; j++) {
          int sg = st * 64 + j * 16 + lr;
#pragma unroll
          for (int r = 0; r < 4; r++) {
            int ll = lbase + r;
            float m = (sg <= ll) ? sacc[j][r] * __expf(Acum[ll] - Acum[sg]) : 0.f;
            Mt[wl0 + q * 4 + r][j * 16 + lr] = f2bf(m);
          }
        }
        __syncthreads();   // publish Mt
#pragma unroll
        for (int ss2 = 0; ss2 < 2; ss2++) {
          s8v a = *(const s8v*)&Mt[wl0 + lr][ss2 * 32 + q * 8];
#pragma unroll
          for (int j = 0; j < 4; j++)
            acc[lt][j] = mfma_bf16(a,
                *(const s8v*)&xdtT[j * 16 + lr][ss2 * 32 + q * 8], acc[lt][j]);
        }
      }
    }
    __syncthreads();   // WAR: B_s/xdtT/Mt reads done before next st
  }

  // epilogue: fold D*x, transpose via Mt (wave-own rows), coalesced store
#pragma unroll
  for (int lt = 0; lt < 4; lt++) {
#pragma unroll
    for (int j = 0; j < 4; j++)
#pragma unroll
      for (int r = 0; r < 4; r++) {
        int lrow = wl0 + q * 4 + r;
        int ll = lt * 64 + lrow;
        int p = j * 16 + lr;
        float xv = bf2f(xBCc[(row0 + ll) * CONVD + h * PDIM + p]);
        Mt[lrow][p] = f2bf(acc[lt][j][r] + Dh * xv);
      }
    __syncthreads();
#pragma unroll
    for (int ps = 0; ps < 2; ps++) {
      int r = ps * 32 + (tid >> 3);
      int c8 = (tid & 7) * 8;
      s8v v = *(const s8v*)&Mt[r][c8];
      *(s8v*)&y[(row0 + lt * 64 + r) * DINNER + h * PDIM + c8] = v;
    }
    __syncthreads();   // WAR before next lt's Mt write
  }
}

// ------------------- gated RMSNorm -> bf16, + folded W_out cast ----------
__global__ __launch_bounds__(256) void norm_cast_kernel(
    const short* __restrict__ y, const short* __restrict__ z,
    const float* __restrict__ norm_w, short* __restrict__ g,
    const float* __restrict__ wsrc, short* __restrict__ wdst) {
  int bl = blockIdx.x, tid = threadIdx.x;
  if (bl >= 4096) {
    int base = (bl - 4096) * 1024 + tid;
#pragma unroll
    for (int i = 0; i < 4; i++) {
      int idx = base + i * 256;
      float4 v = ((const float4*)wsrc)[idx];
      short4 o;
      o.x = f2bf(v.x); o.y = f2bf(v.y); o.z = f2bf(v.z); o.w = f2bf(v.w);
      ((short4*)wdst)[idx] = o;
    }
    return;
  }
  const short4* yrow = (const short4*)(y + (size_t)bl * DINNER);
  const short4* zrow = (const short4*)(z + (size_t)bl * DINNER);
  float gv[16];
  float ss = 0.f;
  for (int i = 0; i < 4; i++) {
    short4 yv = yrow[tid + i * 256];
    short4 zv = zrow[tid + i * 256];
    float zf[4] = {bf2f(zv.x), bf2f(zv.y), bf2f(zv.z), bf2f(zv.w)};
    float yf[4] = {bf2f(yv.x), bf2f(yv.y), bf2f(yv.z), bf2f(yv.w)};
    for (int t = 0; t < 4; t++) {
      float gg = yf[t] * (zf[t] / (1.f + expf(-zf[t])));
      gv[i * 4 + t] = gg;
      ss += gg * gg;
    }
  }
  for (int off = 32; off > 0; off >>= 1) ss += __shfl_down(ss, off);
  __shared__ float red[4];
  __shared__ float rsS;
  if ((tid & 63) == 0) red[tid >> 6] = ss;
  __syncthreads();
  if (tid == 0) rsS = rsqrtf((red[0] + red[1] + red[2] + red[3]) * (1.f / 4096.f) + 1e-5f);
  __syncthreads();
  float rs = rsS;
  for (int i = 0; i < 4; i++) {
    int j4 = (tid + i * 256) * 4;
    float4 nw = *(const float4*)&norm_w[j4];
    short4 o;
    o.x = f2bf(gv[i * 4 + 0] * rs * nw.x);
    o.y = f2bf(gv[i * 4 + 1] * rs * nw.y);
    o.z = f2bf(gv[i * 4 + 2] * rs * nw.z);
    o.w = f2bf(gv[i * 4 + 3] * rs * nw.w);
    *(short4*)&g[(size_t)bl * DINNER + j4] = o;
  }
}

extern "C" void kernel_launch(void* const* d_in, const int* in_sizes, int n_in,
                              void* d_out, int out_size, void* d_ws, size_t ws_size,
                              hipStream_t stream) {
  const float* hidden  = (const float*)d_in[0];
  const float* W_in    = (const float*)d_in[1];
  const float* conv_w  = (const float*)d_in[2];
  const float* conv_b  = (const float*)d_in[3];
  const float* dt_bias = (const float*)d_in[4];
  const float* A_log   = (const float*)d_in[5];
  const float* D_param = (const float*)d_in[6];
  const float* norm_w  = (const float*)d_in[7];
  const float* W_out   = (const float*)d_in[8];
  float* out = (float*)d_out;

  // ---- workspace arena (122,687,488 bytes), phase-overlapped regions ----
  char* ws = (char*)d_ws;
  short* z_bf  = (short*)(ws + 0);                     // 33,554,432
  float* dtb   = (float*)(ws + 33554432);              //  1,048,576
  float* da_l  = (float*)(ws + 34603008);              //  4 KB
  short* xbc_pre = (short*)(ws + 34607104);            // 35,651,584 (GEMM1->conv)
  short* y_bf    = (short*)(ws + 34607104);            // 33,554,432 (ssd_y->norm)
  short* hid_bf  = (short*)(ws + 70258688);            // 16,777,216 (casts->GEMM1)
  short* win_bf  = (short*)(ws + 87035904);            // 34,865,152 (casts->GEMM1)
  short* xBCc    = (short*)(ws + 70258688);            // 35,651,584 (conv->ssd)
  short* states  = (short*)(ws + 105910272);           // 16,777,216 (ssd)
  short* g_bf    = (short*)(ws + 70258688);            // 33,554,432 (norm->GEMM2)
  short* wout_bf = (short*)(ws + 105910272);           // 16,777,216 (cast->GEMM2)
  if (ws_size < (size_t)122687488) return;

  cast_bf16_kernel<<<8192, 256, 0, stream>>>(hidden, hid_bf, 2097152);
  cast_bf16_kernel<<<17024, 256, 0, stream>>>(W_in, win_bf, 4358144);

  gemm1_256<<<544, 512, 0, stream>>>(hid_bf, win_bf, z_bf, xbc_pre, dtb);

  conv_silu_kernel<<<dim3(17, 4096), 256, 0, stream>>>(xbc_pre, conv_w, conv_b, xBCc);
  dt_kernel<<<1024, 256, 0, stream>>>(dtb, dt_bias);

  ssd_states_kernel<<<1024, 256, 0, stream>>>(xBCc, dtb, A_log, states, da_l);
  scan_kernel<<<512, 256, 0, stream>>>(states, da_l);
  ssd_y_kernel<<<1024, 256, 0, stream>>>(xBCc, dtb, A_log, D_param, states, y_bf);

  norm_cast_kernel<<<6144, 256, 0, stream>>>(y_bf, z_bf, norm_w, g_bf, W_out, wout_bf);

  gemm2_256x128<<<256, 512, 0, stream>>>(g_bf, wout_bf, out);
}

// Round 9
// 638.194 us; speedup vs baseline: 1.1190x; 1.0148x over previous
//
#include <hip/hip_runtime.h>

#define SEQLEN 2048
#define NHEADS 64
#define PDIM 64
#define NSTATE 128
#define CSIZE 256
#define NCHUNK 8
#define DINNER 4096
#define CONVD 4352
#define PROJD 8512

using s8v = __attribute__((ext_vector_type(8))) short;
using f4v = __attribute__((ext_vector_type(4))) float;
using bf8v = __attribute__((ext_vector_type(8))) __bf16;

__device__ __forceinline__ short f2bf(float x) {
  union { float f; unsigned u; } t; t.f = x;
  unsigned r = t.u + 0x7FFFu + ((t.u >> 16) & 1u);
  return (short)(r >> 16);
}
__device__ __forceinline__ float bf2f(short s) {
  union { unsigned u; float f; } t;
  t.u = ((unsigned)(unsigned short)s) << 16;
  return t.f;
}

__device__ __forceinline__ f4v mfma_bf16(s8v a, s8v b, f4v c) {
  return __builtin_amdgcn_mfma_f32_16x16x32_bf16(
      __builtin_bit_cast(bf8v, a), __builtin_bit_cast(bf8v, b), c, 0, 0, 0);
}

// async global->LDS, 16B per lane; LDS dest must be lane-contiguous
__device__ __forceinline__ void gll16(const void* g, void* l) {
  __builtin_amdgcn_global_load_lds(
      (const __attribute__((address_space(1))) unsigned*)g,
      (__attribute__((address_space(3))) unsigned*)l, 16, 0, 0);
}

// ---------------------------------------------------------------- casts
__global__ __launch_bounds__(256) void cast_bf16_kernel(
    const float* __restrict__ in, short* __restrict__ out, int n4) {
  int i = blockIdx.x * 256 + threadIdx.x;
  if (i < n4) {
    float4 v = ((const float4*)in)[i];
    short4 o;
    o.x = f2bf(v.x); o.y = f2bf(v.y); o.z = f2bf(v.z); o.w = f2bf(v.w);
    ((short4*)out)[i] = o;
  }
}

// ===================== GEMM1: 256x256 8-phase pipelined (m201 template) ====
// FROZEN at the r1/r2/r6-measured form (182-184us, MfmaUtil 33.4). The
// dt_bias+softplus epilogue fusion poisoned the K-loop codegen (r3-r5 all
// ~239us); any edit to this kernel needs a full A/B. Do not touch.

#define G1_STAGE_A(dst, h, kt) do {                                          \
    _Pragma("unroll")                                                        \
    for (int it_ = 0; it_ < 2; ++it_) {                                      \
      int ci_ = it_ * 512 + tid;                                             \
      int r_ = ci_ >> 3;                                                     \
      int g_ = ((ci_ & 7) ^ (r_ & 7)) << 3;                                  \
      gll16(&A[(size_t)(tm0 + (h) * 128 + r_) * 2048 + (kt) * 64 + g_],      \
            &(dst)[(h) * 8192 + ci_ * 8]);                                   \
    }                                                                        \
  } while (0)

#define G1_STAGE_B(dst, h, kt) do {                                          \
    _Pragma("unroll")                                                        \
    for (int it_ = 0; it_ < 2; ++it_) {                                      \
      int ci_ = it_ * 512 + tid;                                             \
      int r_ = ci_ >> 3;                                                     \
      int g_ = ((ci_ & 7) ^ (r_ & 7)) << 3;                                  \
      int br_ = tn0 + (h) * 128 + r_;                                        \
      if (br_ > 8511) br_ = 8511; /* dt-strip tile over-reads: clamp */      \
      gll16(&B[(size_t)br_ * 2048 + (kt) * 64 + g_],                         \
            &(dst)[(h) * 8192 + ci_ * 8]);                                   \
    }                                                                        \
  } while (0)

#define RD_A(m, ks) \
  (*(const s8v*)&Ad[(wm + (m) * 16 + lr) * 64 + (((ks) * 4 + q) ^ sw7) * 8])
#define RD_B(n, ks) \
  (*(const s8v*)&Bd[(wn + (n) * 16 + lr) * 64 + (((ks) * 4 + q) ^ sw7) * 8])

#define G1_MFMA2(m0, x00, x01, x10, x11) do {                                \
    __builtin_amdgcn_s_setprio(1);                                           \
    _Pragma("unroll") for (int n = 0; n < 4; ++n)                            \
      acc[m0][n] = mfma_bf16(x00, bk0[n], acc[m0][n]);                       \
    _Pragma("unroll") for (int n = 0; n < 4; ++n)                            \
      acc[m0][n] = mfma_bf16(x01, bk1[n], acc[m0][n]);                       \
    _Pragma("unroll") for (int n = 0; n < 4; ++n)                            \
      acc[(m0) + 1][n] = mfma_bf16(x10, bk0[n], acc[(m0) + 1][n]);           \
    _Pragma("unroll") for (int n = 0; n < 4; ++n)                            \
      acc[(m0) + 1][n] = mfma_bf16(x11, bk1[n], acc[(m0) + 1][n]);           \
    __builtin_amdgcn_s_setprio(0);                                           \
  } while (0)

__global__ __launch_bounds__(512, 2) void gemm1_256(
    const short* __restrict__ A, const short* __restrict__ B,
    short* __restrict__ z, short* __restrict__ xbc, float* __restrict__ dtb) {
  const int NT = 32;  // 2048 / 64
  // XCD-bijective swizzle (544 % 8 == 0) then 4-high panel map for L2 reuse
  const int bid = blockIdx.x;
  const int sid = (bid & 7) * 68 + (bid >> 3);
  const int panel = sid / 136, rem = sid % 136;
  const int bx = rem >> 2, by = panel * 4 + (rem & 3);
  const int tm0 = by * 256, tn0 = bx * 256;
  __shared__ alignas(16) short lds[65536];  // 128 KB
  const int tid = threadIdx.x;
  const int lane = tid & 63, wid = tid >> 6;
  const int wm = (wid >> 2) * 128, wn = (wid & 3) * 64;
  const int lr = lane & 15, q = lane >> 4;
  const int sw7 = lr & 7;

  f4v acc[8][4];
#pragma unroll
  for (int m = 0; m < 8; ++m)
#pragma unroll
    for (int n = 0; n < 4; ++n)
#pragma unroll
      for (int r = 0; r < 4; ++r) acc[m][n][r] = 0.f;

  // prologue: tile0 {Ah0,Ah1,Bh0,Bh1}, tile1 {Bh0,Bh1}  (12 loads/thread)
  {
    short* A0 = lds;
    short* B0 = lds + 16384;
    short* B1 = lds + 49152;
    G1_STAGE_A(A0, 0, 0); G1_STAGE_A(A0, 1, 0);
    G1_STAGE_B(B0, 0, 0); G1_STAGE_B(B0, 1, 0);
    G1_STAGE_B(B1, 0, 1); G1_STAGE_B(B1, 1, 1);
    // drain A(0),B(0); leave B(1) in flight
    asm volatile("s_waitcnt vmcnt(4)" ::: "memory");
    __builtin_amdgcn_s_barrier();
  }

  for (int t = 0; t < NT; ++t) {
    short* Ad = lds + ((t & 1) << 15);
    short* Bd = Ad + 16384;
    short* An = lds + (((t + 1) & 1) << 15);
    s8v bk0[4], bk1[4];
    // ---- p0: all B-frags + a0,a1; stage Ah0(t+1)
    {
#pragma unroll
      for (int n = 0; n < 4; ++n) { bk0[n] = RD_B(n, 0); bk1[n] = RD_B(n, 1); }
      s8v a00 = RD_A(0, 0), a01 = RD_A(0, 1);
      s8v a10 = RD_A(1, 0), a11 = RD_A(1, 1);
      if (t + 1 < NT) G1_STAGE_A(An, 0, t + 1);
      __builtin_amdgcn_s_barrier();
      asm volatile("s_waitcnt lgkmcnt(0)" ::: "memory");
      G1_MFMA2(0, a00, a01, a10, a11);
      __builtin_amdgcn_s_barrier();
    }
    // ---- p1
    {
      s8v a00 = RD_A(2, 0), a01 = RD_A(2, 1);
      s8v a10 = RD_A(3, 0), a11 = RD_A(3, 1);
      if (t + 1 < NT) G1_STAGE_A(An, 1, t + 1);
      __builtin_amdgcn_s_barrier();
      asm volatile("s_waitcnt lgkmcnt(0)" ::: "memory");
      G1_MFMA2(2, a00, a01, a10, a11);
      __builtin_amdgcn_s_barrier();
    }
    // ---- p2: B(t+2) h0 into CURRENT B region (dead after p0 reads)
    {
      s8v a00 = RD_A(4, 0), a01 = RD_A(4, 1);
      s8v a10 = RD_A(5, 0), a11 = RD_A(5, 1);
      if (t + 2 < NT) G1_STAGE_B(Bd, 0, t + 2);
      __builtin_amdgcn_s_barrier();
      asm volatile("s_waitcnt lgkmcnt(0)" ::: "memory");
      G1_MFMA2(4, a00, a01, a10, a11);
      __builtin_amdgcn_s_barrier();
    }
    // ---- p3: counted vmcnt validates tile t+1 for p0(t+1)'s reads
    {
      s8v a00 = RD_A(6, 0), a01 = RD_A(6, 1);
      s8v a10 = RD_A(7, 0), a11 = RD_A(7, 1);
      if (t + 2 < NT) G1_STAGE_B(Bd, 1, t + 2);
      if (t < NT - 2) {
        asm volatile("s_waitcnt vmcnt(4)" ::: "memory");
      } else {
        asm volatile("s_waitcnt vmcnt(0)" ::: "memory");
      }
      __builtin_amdgcn_s_barrier();
      asm volatile("s_waitcnt lgkmcnt(0)" ::: "memory");
      G1_MFMA2(6, a00, a01, a10, a11);
      __builtin_amdgcn_s_barrier();
    }
  }

  // ------------------------------ epilogue ------------------------------
  if (bx == 33) {  // dt strip: cols 8448..8511, fp32, wn==0 waves hold them
    if (wn == 0) {
#pragma unroll
      for (int m = 0; m < 8; ++m)
#pragma unroll
        for (int n = 0; n < 4; ++n) {
          int col = n * 16 + lr;
#pragma unroll
          for (int r = 0; r < 4; ++r) {
            int row = tm0 + wm + m * 16 + q * 4 + r;
            dtb[(size_t)row * NHEADS + col] = acc[m][n][r];
          }
        }
    }
    return;
  }
  short* outp; int stride, colbase;
  if (bx < 16) { outp = z;   stride = DINNER; colbase = tn0; }
  else         { outp = xbc; stride = CONVD;  colbase = tn0 - DINNER; }
  short* Cs = lds;  // [128][264] bf16 staging, all pipeline work drained
  for (int h = 0; h < 2; ++h) {
    __syncthreads();
    if ((wid >> 2) == h) {
#pragma unroll
      for (int m = 0; m < 8; ++m)
#pragma unroll
        for (int n = 0; n < 4; ++n)
#pragma unroll
          for (int r = 0; r < 4; ++r)
            Cs[(m * 16 + q * 4 + r) * 264 + wn + n * 16 + lr] =
                f2bf(acc[m][n][r]);
    }
    __syncthreads();
#pragma unroll
    for (int itr = 0; itr < 8; ++itr) {
      int idx = itr * 512 + tid;
      int r = idx >> 5, c8 = (idx & 31) * 8;
      s8v v = *(const s8v*)&Cs[r * 264 + c8];
      *(s8v*)&outp[(size_t)(tm0 + h * 128 + r) * stride + colbase + c8] = v;
    }
  }
}

// ======== GEMM2: 256x128-tile 8-phase, grid 256 = EXACTLY 1 round =========
// out = g @ W_out^T. M=4096, N=2048, K=4096. Block 512 thr (8 waves 2Mx4N,
// per-wave out 128x32). LDS 96KB: buf[2] x { A[256][64], B[128][64] }.

#define G2_STAGE_A(dst, h, kt) do {                                          \
    _Pragma("unroll")                                                        \
    for (int it_ = 0; it_ < 2; ++it_) {                                      \
      int ci_ = it_ * 512 + tid;                                             \
      int r_ = ci_ >> 3;                                                     \
      int g_ = ((ci_ & 7) ^ (r_ & 7)) << 3;                                  \
      gll16(&Ag[(size_t)(tm0 + (h) * 128 + r_) * 4096 + (kt) * 64 + g_],     \
            &(dst)[(h) * 8192 + ci_ * 8]);                                   \
    }                                                                        \
  } while (0)

#define G2_STAGE_B(dst, h, kt) do {                                          \
    int ci_ = tid;                                                           \
    int r_ = ci_ >> 3;                                                       \
    int g_ = ((ci_ & 7) ^ (r_ & 7)) << 3;                                    \
    gll16(&Bg[(size_t)(tn0 + (h) * 64 + r_) * 4096 + (kt) * 64 + g_],        \
          &(dst)[(h) * 4096 + ci_ * 8]);                                     \
  } while (0)

#define RD_A2(m, ks) \
  (*(const s8v*)&Ad[(wm + (m) * 16 + lr) * 64 + (((ks) * 4 + q) ^ sw7) * 8])
#define RD_B2(n, ks) \
  (*(const s8v*)&Bd[(wn + (n) * 16 + lr) * 64 + (((ks) * 4 + q) ^ sw7) * 8])

#define G2_MFMA2(m0, x00, x01, x10, x11) do {                                \
    __builtin_amdgcn_s_setprio(1);                                           \
    _Pragma("unroll") for (int n = 0; n < 2; ++n)                            \
      acc[m0][n] = mfma_bf16(x00, bk0[n], acc[m0][n]);                       \
    _Pragma("unroll") for (int n = 0; n < 2; ++n)                            \
      acc[m0][n] = mfma_bf16(x01, bk1[n], acc[m0][n]);                       \
    _Pragma("unroll") for (int n = 0; n < 2; ++n)                            \
      acc[(m0) + 1][n] = mfma_bf16(x10, bk0[n], acc[(m0) + 1][n]);           \
    _Pragma("unroll") for (int n = 0; n < 2; ++n)                            \
      acc[(m0) + 1][n] = mfma_bf16(x11, bk1[n], acc[(m0) + 1][n]);           \
    __builtin_amdgcn_s_setprio(0);                                           \
  } while (0)

__global__ __launch_bounds__(512, 2) void gemm2_256x128(
    const short* __restrict__ Ag, const short* __restrict__ Bg,
    float* __restrict__ C) {
  const int NT = 64;  // 4096 / 64
  // XCD-bijective swizzle (256 % 8 == 0), 4-high panels
  const int bid = blockIdx.x;
  const int sid = (bid & 7) * 32 + (bid >> 3);
  const int panel = sid >> 6, rem = sid & 63;
  const int bx = rem >> 2, by = panel * 4 + (rem & 3);
  const int tm0 = by * 256, tn0 = bx * 128;
  __shared__ alignas(16) short lds[49152];  // 96 KB
  const int tid = threadIdx.x;
  const int lane = tid & 63, wid = tid >> 6;
  const int wm = (wid >> 2) * 128, wn = (wid & 3) * 32;
  const int lr = lane & 15, q = lane >> 4;
  const int sw7 = lr & 7;

  f4v acc[8][2];
#pragma unroll
  for (int m = 0; m < 8; ++m)
#pragma unroll
    for (int n = 0; n < 2; ++n)
#pragma unroll
      for (int r = 0; r < 4; ++r) acc[m][n][r] = 0.f;

  // prologue: A0 h0,h1 (4) + B0 h0,h1 (2) + B1 h0,h1 (2)
  {
    short* A0 = lds;
    short* B0 = lds + 16384;
    short* B1 = lds + 40960;
    G2_STAGE_A(A0, 0, 0); G2_STAGE_A(A0, 1, 0);
    G2_STAGE_B(B0, 0, 0); G2_STAGE_B(B0, 1, 0);
    G2_STAGE_B(B1, 0, 1); G2_STAGE_B(B1, 1, 1);
    asm volatile("s_waitcnt vmcnt(2)" ::: "memory");  // leave B(1) in flight
    __builtin_amdgcn_s_barrier();
  }

  for (int t = 0; t < NT; ++t) {
    short* Ad = lds + (t & 1) * 24576;
    short* Bd = Ad + 16384;
    short* An = lds + ((t + 1) & 1) * 24576;
    s8v bk0[2], bk1[2];
    // ---- p0
    {
#pragma unroll
      for (int n = 0; n < 2; ++n) { bk0[n] = RD_B2(n, 0); bk1[n] = RD_B2(n, 1); }
      s8v a00 = RD_A2(0, 0), a01 = RD_A2(0, 1);
      s8v a10 = RD_A2(1, 0), a11 = RD_A2(1, 1);
      if (t + 1 < NT) G2_STAGE_A(An, 0, t + 1);
      __builtin_amdgcn_s_barrier();
      asm volatile("s_waitcnt lgkmcnt(0)" ::: "memory");
      G2_MFMA2(0, a00, a01, a10, a11);
      __builtin_amdgcn_s_barrier();
    }
    // ---- p1
    {
      s8v a00 = RD_A2(2, 0), a01 = RD_A2(2, 1);
      s8v a10 = RD_A2(3, 0), a11 = RD_A2(3, 1);
      if (t + 1 < NT) G2_STAGE_A(An, 1, t + 1);
      __builtin_amdgcn_s_barrier();
      asm volatile("s_waitcnt lgkmcnt(0)" ::: "memory");
      G2_MFMA2(2, a00, a01, a10, a11);
      __builtin_amdgcn_s_barrier();
    }
    // ---- p2: B(t+2) h0 into CURRENT B region (dead after p0 reads)
    {
      s8v a00 = RD_A2(4, 0), a01 = RD_A2(4, 1);
      s8v a10 = RD_A2(5, 0), a11 = RD_A2(5, 1);
      if (t + 2 < NT) G2_STAGE_B(Bd, 0, t + 2);
      __builtin_amdgcn_s_barrier();
      asm volatile("s_waitcnt lgkmcnt(0)" ::: "memory");
      G2_MFMA2(4, a00, a01, a10, a11);
      __builtin_amdgcn_s_barrier();
    }
    // ---- p3: counted vmcnt validates tile t+1
    {
      s8v a00 = RD_A2(6, 0), a01 = RD_A2(6, 1);
      s8v a10 = RD_A2(7, 0), a11 = RD_A2(7, 1);
      if (t + 2 < NT) G2_STAGE_B(Bd, 1, t + 2);
      if (t < NT - 2) {
        asm volatile("s_waitcnt vmcnt(2)" ::: "memory");
      } else {
        asm volatile("s_waitcnt vmcnt(0)" ::: "memory");
      }
      __builtin_amdgcn_s_barrier();
      asm volatile("s_waitcnt lgkmcnt(0)" ::: "memory");
      G2_MFMA2(6, a00, a01, a10, a11);
      __builtin_amdgcn_s_barrier();
    }
  }

  // epilogue: fp32 dword scatter (64B/quarter-wave segments)
#pragma unroll
  for (int m = 0; m < 8; ++m)
#pragma unroll
    for (int n = 0; n < 2; ++n) {
      int r0 = tm0 + wm + m * 16 + q * 4;
      int c0 = tn0 + wn + n * 16 + lr;
#pragma unroll
      for (int r = 0; r < 4; ++r)
        C[(size_t)(r0 + r) * 2048 + c0] = acc[m][n][r];
    }
}

// ========== fused depthwise conv+SiLU (8-ch vectorized) + dt softplus =====
// blocks [0, 8704): conv — 4096 (b,l) rows x 544 groups of 8 channels,
// flat item id, s8v 16B loads per tap (was 1 output/thread scalar 2B).
// blocks [8704, 9728): dt softplus in-place (was separate dt_kernel).
__global__ __launch_bounds__(256) void conv_dt_kernel(
    const short* __restrict__ xbc, const float* __restrict__ conv_w,
    const float* __restrict__ conv_b, short* __restrict__ xBCc,
    float* __restrict__ dtb, const float* __restrict__ dt_bias) {
  const int bid = blockIdx.x;
  if (bid >= 8704) {  // ---- dt region
    int idx = (bid - 8704) * 256 + threadIdx.x;  // < 4096*64
    int hh = idx & 63;
    float v = dtb[idx] + dt_bias[hh];
    dtb[idx] = (v > 20.f) ? v : log1pf(expf(v));
    return;
  }
  int item = bid * 256 + threadIdx.x;  // < 4096*544
  int bl = item / 544;                 // (b,l) row
  int c8 = item - bl * 544;            // 8-channel group
  int cc0 = c8 * 8;
  int b = bl >> 11, l = bl & 2047;
  // weights: 8 channels x 4 taps (fp32, L2-resident: 70KB total)
  float wk[8][4];
#pragma unroll
  for (int j = 0; j < 8; ++j) {
    float4 wv = *(const float4*)&conv_w[(cc0 + j) * 4];
    wk[j][0] = wv.x; wk[j][1] = wv.y; wk[j][2] = wv.z; wk[j][3] = wv.w;
  }
  float acc[8];
  float4 b0 = *(const float4*)&conv_b[cc0];
  float4 b1 = *(const float4*)&conv_b[cc0 + 4];
  acc[0] = b0.x; acc[1] = b0.y; acc[2] = b0.z; acc[3] = b0.w;
  acc[4] = b1.x; acc[5] = b1.y; acc[6] = b1.z; acc[7] = b1.w;
  const short* pbase = xbc + (size_t)(b * SEQLEN) * CONVD + cc0;
#pragma unroll
  for (int k = 0; k < 4; ++k) {
    int ls = l - 3 + k;
    if (ls >= 0) {
      s8v x = *(const s8v*)&pbase[(size_t)ls * CONVD];
#pragma unroll
      for (int j = 0; j < 8; ++j) acc[j] += bf2f(x[j]) * wk[j][k];
    }
  }
  short o[8];
#pragma unroll
  for (int j = 0; j < 8; ++j) {
    float sv = acc[j] / (1.f + expf(-acc[j]));
    o[j] = f2bf(sv);
  }
  *(s8v*)&xBCc[(size_t)bl * CONVD + cc0] = *(const s8v*)o;
}

// ---------------------------------------- per-chunk states (fp32 VALU)
__global__ __launch_bounds__(256) void ssd_states_kernel(
    const short* __restrict__ xBCc, const float* __restrict__ dtp,
    const float* __restrict__ A_log, short* __restrict__ states,
    float* __restrict__ da_last) {
  const int blk = blockIdx.x;
  const int h = blk & 63, cc = (blk >> 6) & 7, b = blk >> 9;
  const int tid = threadIdx.x;
  __shared__ float dt_s[CSIZE], Acum[CSIZE], w_s[CSIZE];
  __shared__ float xw[64][64];
  __shared__ float Bt[64][NSTATE];
  const size_t row0 = (size_t)(b * SEQLEN + cc * CSIZE);
  dt_s[tid] = dtp[(row0 + tid) * NHEADS + h];
  __syncthreads();
  if (tid == 0) {
    float Aval = -expf(A_log[h]);
    float s = 0.f;
    for (int i = 0; i < CSIZE; i++) { s += dt_s[i]; Acum[i] = s * Aval; }
    da_last[(size_t)(b * NHEADS + h) * NCHUNK + cc] = Acum[CSIZE - 1];
  }
  __syncthreads();
  float total = Acum[CSIZE - 1];
  w_s[tid] = dt_s[tid] * expf(total - Acum[tid]);
  float acc[4][8];
  for (int a = 0; a < 4; a++) for (int j = 0; j < 8; j++) acc[a][j] = 0.f;
  const int pi = (tid & 15) * 4, ni = (tid >> 4) * 8;
  for (int lt = 0; lt < 4; lt++) {
    __syncthreads();
    for (int i = 0; i < 4; i++) {
      int idx = tid + i * 256;
      int r = idx >> 4, c4 = (idx & 15) << 2;
      short4 v = *(const short4*)&xBCc[(row0 + lt * 64 + r) * CONVD + h * PDIM + c4];
      float wl = w_s[lt * 64 + r];
      xw[r][c4 + 0] = bf2f(v.x) * wl;
      xw[r][c4 + 1] = bf2f(v.y) * wl;
      xw[r][c4 + 2] = bf2f(v.z) * wl;
      xw[r][c4 + 3] = bf2f(v.w) * wl;
    }
    for (int i = 0; i < 8; i++) {
      int idx = tid + i * 256;
      int r = idx >> 5, c4 = (idx & 31) << 2;
      short4 v = *(const short4*)&xBCc[(row0 + lt * 64 + r) * CONVD + DINNER + c4];
      Bt[r][c4 + 0] = bf2f(v.x);
      Bt[r][c4 + 1] = bf2f(v.y);
      Bt[r][c4 + 2] = bf2f(v.z);
      Bt[r][c4 + 3] = bf2f(v.w);
    }
    __syncthreads();
    for (int l = 0; l < 64; l++) {
      float4 xv = *(const float4*)&xw[l][pi];
      float4 b0 = *(const float4*)&Bt[l][ni];
      float4 b1 = *(const float4*)&Bt[l][ni + 4];
      float xa[4] = {xv.x, xv.y, xv.z, xv.w};
      float bb[8] = {b0.x, b0.y, b0.z, b0.w, b1.x, b1.y, b1.z, b1.w};
      for (int a = 0; a < 4; a++)
        for (int j = 0; j < 8; j++)
          acc[a][j] += xa[a] * bb[j];
    }
  }
  const size_t sbase = (((size_t)b * NCHUNK + cc) * NHEADS + h) * (PDIM * NSTATE);
  for (int a = 0; a < 4; a++) {
    short o[8];
    for (int j = 0; j < 8; j++) o[j] = f2bf(acc[a][j]);
    *(s8v*)&states[sbase + (size_t)(pi + a) * NSTATE + ni] = *(const s8v*)o;
  }
}

// ---------------- 8-step chunk scan (in-place, s8v vectorized) -----------
__global__ __launch_bounds__(256) void scan_kernel(
    short* __restrict__ states, const float* __restrict__ da_last) {
  const int bh = blockIdx.x >> 2, sl = blockIdx.x & 3;
  const int b = bh >> 6, h = bh & 63;
  const int tid = threadIdx.x;
  float prev[8];
#pragma unroll
  for (int i = 0; i < 8; i++) prev[i] = 0.f;
  for (int c = 0; c < NCHUNK; c++) {
    const size_t base = (((size_t)b * NCHUNK + c) * NHEADS + h) * (PDIM * NSTATE)
                      + sl * 2048;
    const float d = expf(da_last[(size_t)bh * NCHUNK + c]);
    size_t e0 = base + (size_t)tid * 8;
    s8v sv = *(const s8v*)&states[e0];
    short ov[8];
#pragma unroll
    for (int i = 0; i < 8; i++) {
      float s = bf2f(sv[i]);
      ov[i] = f2bf(prev[i]);
      prev[i] = prev[i] * d + s;
    }
    *(s8v*)&states[e0] = *(const s8v*)ov;
  }
}

// ------------- SSD Y v1 (r6-measured form in the 638us config) -----------
// v2/v3 st-outer restructures both lost (scratch bug r7; +9us VGPR/serial
// chain r8). Keep v1.
__global__ __launch_bounds__(256) void ssd_y_kernel(
    const short* __restrict__ xBCc, const float* __restrict__ dtp,
    const float* __restrict__ A_log, const float* __restrict__ D_param,
    const short* __restrict__ prevs, short* __restrict__ y) {
  const int blk = blockIdx.x;
  const int h = blk & 63, cc = (blk >> 6) & 7, b = blk >> 9;
  const int tid = threadIdx.x;
  const int lane = tid & 63, w = tid >> 6;
  const int lr = lane & 15, q = lane >> 4;
  __shared__ float dt_s[CSIZE];
  __shared__ float Acum[CSIZE];
  __shared__ short C_s[64][136];
  __shared__ short BP_s[64][136];
  __shared__ short xdtT[64][72];
  __shared__ short Mt[64][72];
  const size_t row0 = (size_t)(b * SEQLEN + cc * CSIZE);
  dt_s[tid] = dtp[(row0 + tid) * NHEADS + h];
  __syncthreads();
  if (tid == 0) {
    float Aval = -expf(A_log[h]);
    float s = 0.f;
    for (int i = 0; i < CSIZE; i++) { s += dt_s[i]; Acum[i] = s * Aval; }
  }
  const float Dh = D_param[h];
  const size_t prevbase = (((size_t)b * NCHUNK + cc) * NHEADS + h) * (PDIM * NSTATE);
  const int wl0 = w * 16;

  for (int lt = 0; lt < 4; lt++) {
    __syncthreads();
    for (int i = 0; i < 4; i++) {
      int idx = tid + i * 256;
      int r = idx >> 4, c8 = (idx & 15) << 3;
      *(s8v*)&C_s[r][c8] =
          *(const s8v*)&xBCc[(row0 + lt * 64 + r) * CONVD + DINNER + NSTATE + c8];
      *(s8v*)&BP_s[r][c8] = *(const s8v*)&prevs[prevbase + (size_t)r * NSTATE + c8];
    }
    __syncthreads();
    // phase A: acc = C @ prev^T  (K = n = 128)
    f4v acc[4];
    for (int j = 0; j < 4; j++) for (int r = 0; r < 4; r++) acc[j][r] = 0.f;
    for (int ks = 0; ks < 4; ks++) {
      s8v a = *(const s8v*)&C_s[wl0 + lr][ks * 32 + q * 8];
      for (int j = 0; j < 4; j++) {
        s8v bb = *(const s8v*)&BP_s[j * 16 + lr][ks * 32 + q * 8];
        acc[j] = mfma_bf16(a, bb, acc[j]);
      }
    }
    for (int r = 0; r < 4; r++) {
      float e = __expf(Acum[lt * 64 + wl0 + q * 4 + r]);
      for (int j = 0; j < 4; j++) acc[j][r] *= e;
    }
    // phase B: causal s-tiles
    for (int st = 0; st <= lt; st++) {
      __syncthreads();
      for (int i = 0; i < 4; i++) {
        int idx = tid + i * 256;
        int r = idx >> 4, c8 = (idx & 15) << 3;
        *(s8v*)&BP_s[r][c8] =
            *(const s8v*)&xBCc[(row0 + st * 64 + r) * CONVD + DINNER + c8];
      }
      for (int i = 0; i < 4; i++) {
        int idx = tid + i * 256;
        int r = idx >> 4, c4 = (idx & 15) << 2;
        float dtv = dt_s[st * 64 + r];
        short4 v = *(const short4*)&xBCc[(row0 + st * 64 + r) * CONVD + h * PDIM + c4];
        xdtT[c4 + 0][r] = f2bf(bf2f(v.x) * dtv);
        xdtT[c4 + 1][r] = f2bf(bf2f(v.y) * dtv);
        xdtT[c4 + 2][r] = f2bf(bf2f(v.z) * dtv);
        xdtT[c4 + 3][r] = f2bf(bf2f(v.w) * dtv);
      }
      __syncthreads();
      f4v sacc[4];
      for (int j = 0; j < 4; j++) for (int r = 0; r < 4; r++) sacc[j][r] = 0.f;
      for (int ks = 0; ks < 4; ks++) {
        s8v a = *(const s8v*)&C_s[wl0 + lr][ks * 32 + q * 8];
        for (int j = 0; j < 4; j++) {
          s8v bb = *(const s8v*)&BP_s[j * 16 + lr][ks * 32 + q * 8];
          sacc[j] = mfma_bf16(a, bb, sacc[j]);
        }
      }
      int lbase = lt * 64 + wl0 + q * 4;
      for (int j = 0; j < 4; j++) {
        int sg = st * 64 + j * 16 + lr;
        for (int r = 0; r < 4; r++) {
          int ll = lbase + r;
          float m = (sg <= ll) ? sacc[j][r] * __expf(Acum[ll] - Acum[sg]) : 0.f;
          Mt[wl0 + q * 4 + r][j * 16 + lr] = f2bf(m);
        }
      }
      __syncthreads();
      for (int ss2 = 0; ss2 < 2; ss2++) {
        s8v a = *(const s8v*)&Mt[wl0 + lr][ss2 * 32 + q * 8];
        for (int j = 0; j < 4; j++) {
          s8v bb = *(const s8v*)&xdtT[j * 16 + lr][ss2 * 32 + q * 8];
          acc[j] = mfma_bf16(a, bb, acc[j]);
        }
      }
    }
    // epilogue: fold D*x, transpose via Mt (wave-own rows), coalesced store
    for (int j = 0; j < 4; j++)
      for (int r = 0; r < 4; r++) {
        int lrow = wl0 + q * 4 + r;
        int ll = lt * 64 + lrow;
        int p = j * 16 + lr;
        float xv = bf2f(xBCc[(row0 + ll) * CONVD + h * PDIM + p]);
        Mt[lrow][p] = f2bf(acc[j][r] + Dh * xv);
      }
    __syncthreads();
    for (int ps = 0; ps < 2; ps++) {
      int r = ps * 32 + (tid >> 3);
      int c8 = (tid & 7) * 8;
      s8v v = *(const s8v*)&Mt[r][c8];
      *(s8v*)&y[(row0 + lt * 64 + r) * DINNER + h * PDIM + c8] = v;
    }
  }
}

// ------------------- gated RMSNorm -> bf16, + folded W_out cast ----------
__global__ __launch_bounds__(256) void norm_cast_kernel(
    const short* __restrict__ y, const short* __restrict__ z,
    const float* __restrict__ norm_w, short* __restrict__ g,
    const float* __restrict__ wsrc, short* __restrict__ wdst) {
  int bl = blockIdx.x, tid = threadIdx.x;
  if (bl >= 4096) {
    int base = (bl - 4096) * 1024 + tid;
#pragma unroll
    for (int i = 0; i < 4; i++) {
      int idx = base + i * 256;
      float4 v = ((const float4*)wsrc)[idx];
      short4 o;
      o.x = f2bf(v.x); o.y = f2bf(v.y); o.z = f2bf(v.z); o.w = f2bf(v.w);
      ((short4*)wdst)[idx] = o;
    }
    return;
  }
  const short4* yrow = (const short4*)(y + (size_t)bl * DINNER);
  const short4* zrow = (const short4*)(z + (size_t)bl * DINNER);
  float gv[16];
  float ss = 0.f;
  for (int i = 0; i < 4; i++) {
    short4 yv = yrow[tid + i * 256];
    short4 zv = zrow[tid + i * 256];
    float zf[4] = {bf2f(zv.x), bf2f(zv.y), bf2f(zv.z), bf2f(zv.w)};
    float yf[4] = {bf2f(yv.x), bf2f(yv.y), bf2f(yv.z), bf2f(yv.w)};
    for (int t = 0; t < 4; t++) {
      float gg = yf[t] * (zf[t] / (1.f + expf(-zf[t])));
      gv[i * 4 + t] = gg;
      ss += gg * gg;
    }
  }
  for (int off = 32; off > 0; off >>= 1) ss += __shfl_down(ss, off);
  __shared__ float red[4];
  __shared__ float rsS;
  if ((tid & 63) == 0) red[tid >> 6] = ss;
  __syncthreads();
  if (tid == 0) rsS = rsqrtf((red[0] + red[1] + red[2] + red[3]) * (1.f / 4096.f) + 1e-5f);
  __syncthreads();
  float rs = rsS;
  for (int i = 0; i < 4; i++) {
    int j4 = (tid + i * 256) * 4;
    float4 nw = *(const float4*)&norm_w[j4];
    short4 o;
    o.x = f2bf(gv[i * 4 + 0] * rs * nw.x);
    o.y = f2bf(gv[i * 4 + 1] * rs * nw.y);
    o.z = f2bf(gv[i * 4 + 2] * rs * nw.z);
    o.w = f2bf(gv[i * 4 + 3] * rs * nw.w);
    *(short4*)&g[(size_t)bl * DINNER + j4] = o;
  }
}

extern "C" void kernel_launch(void* const* d_in, const int* in_sizes, int n_in,
                              void* d_out, int out_size, void* d_ws, size_t ws_size,
                              hipStream_t stream) {
  const float* hidden  = (const float*)d_in[0];
  const float* W_in    = (const float*)d_in[1];
  const float* conv_w  = (const float*)d_in[2];
  const float* conv_b  = (const float*)d_in[3];
  const float* dt_bias = (const float*)d_in[4];
  const float* A_log   = (const float*)d_in[5];
  const float* D_param = (const float*)d_in[6];
  const float* norm_w  = (const float*)d_in[7];
  const float* W_out   = (const float*)d_in[8];
  float* out = (float*)d_out;

  // ---- workspace arena (122,687,488 bytes), phase-overlapped regions ----
  char* ws = (char*)d_ws;
  short* z_bf  = (short*)(ws + 0);                     // 33,554,432
  float* dtb   = (float*)(ws + 33554432);              //  1,048,576
  float* da_l  = (float*)(ws + 34603008);              //  4 KB
  short* xbc_pre = (short*)(ws + 34607104);            // 35,651,584 (GEMM1->conv)
  short* y_bf    = (short*)(ws + 34607104);            // 33,554,432 (ssd_y->norm)
  short* hid_bf  = (short*)(ws + 70258688);            // 16,777,216 (casts->GEMM1)
  short* win_bf  = (short*)(ws + 87035904);            // 34,865,152 (casts->GEMM1)
  short* xBCc    = (short*)(ws + 70258688);            // 35,651,584 (conv->ssd)
  short* states  = (short*)(ws + 105910272);           // 16,777,216 (ssd)
  short* g_bf    = (short*)(ws + 70258688);            // 33,554,432 (norm->GEMM2)
  short* wout_bf = (short*)(ws + 105910272);           // 16,777,216 (cast->GEMM2)
  if (ws_size < (size_t)122687488) return;

  cast_bf16_kernel<<<8192, 256, 0, stream>>>(hidden, hid_bf, 2097152);
  cast_bf16_kernel<<<17024, 256, 0, stream>>>(W_in, win_bf, 4358144);

  gemm1_256<<<544, 512, 0, stream>>>(hid_bf, win_bf, z_bf, xbc_pre, dtb);

  conv_dt_kernel<<<9728, 256, 0, stream>>>(xbc_pre, conv_w, conv_b, xBCc,
                                           dtb, dt_bias);

  ssd_states_kernel<<<1024, 256, 0, stream>>>(xBCc, dtb, A_log, states, da_l);
  scan_kernel<<<512, 256, 0, stream>>>(states, da_l);
  ssd_y_kernel<<<1024, 256, 0, stream>>>(xBCc, dtb, A_log, D_param, states, y_bf);

  norm_cast_kernel<<<6144, 256, 0, stream>>>(y_bf, z_bf, norm_w, g_bf, W_out, wout_bf);

  gemm2_256x128<<<256, 512, 0, stream>>>(g_bf, wout_bf, out);
}